// Round 2
// baseline (691.467 us; speedup 1.0000x reference)
//
#include <hip/hip_runtime.h>
#include <cstdint>
#include <cstddef>

#define D_MODEL 1024
#define SEQ_LEN 4096
#define NBATCH  4
#define M_ROWS  (NBATCH * SEQ_LEN)   // 16384 rows (b*4096+n)
#define NCHUNK  64
#define CHLEN   64                   // SEQ_LEN / NCHUNK
#define GN_EPS_F 0.00064f

typedef unsigned short u16;
typedef __attribute__((ext_vector_type(4))) float f32x4;
typedef __attribute__((ext_vector_type(8))) __bf16 bf16x8;

enum { ACT_DECAY = 0, ACT_TANH, ACT_VMUL, ACT_U, ACT_SIG, ACT_BIAS };

__device__ __forceinline__ u16 f2bf(float f) {
  union { float f; uint32_t u; } un; un.f = f;
  uint32_t r = (un.u + 0x7FFFu + ((un.u >> 16) & 1u)) >> 16;  // RNE
  return (u16)r;
}
__device__ __forceinline__ float bf2f(u16 h) {
  union { uint32_t u; float f; } un; un.u = ((uint32_t)h) << 16;
  return un.f;
}
__device__ __forceinline__ float sigm(float y) { return 1.f / (1.f + expf(-y)); }

// ---------------- weights f32 -> bf16 (7 matrices, contiguous slots) ----------
__global__ __launch_bounds__(256) void wconv(
    const float* __restrict__ w0, const float* __restrict__ w1,
    const float* __restrict__ w2, const float* __restrict__ w3,
    const float* __restrict__ w4, const float* __restrict__ w5,
    const float* __restrict__ w6, u16* __restrict__ Wb) {
  const int gid = blockIdx.x * 256 + threadIdx.x;  // over 7*262144 float4s
  const int m = gid >> 18;
  const int off = gid & 262143;
  const float* src;
  switch (m) {
    case 0: src = w0; break; case 1: src = w1; break; case 2: src = w2; break;
    case 3: src = w3; break; case 4: src = w4; break; case 5: src = w5; break;
    default: src = w6; break;
  }
  const float4 v = ((const float4*)src)[off];
  ushort4 o;
  o.x = f2bf(v.x); o.y = f2bf(v.y); o.z = f2bf(v.z); o.w = f2bf(v.w);
  ((ushort4*)Wb)[gid] = o;
}

// ---------------- z = x + (prev - x) * mix  -> bf16 ---------------------------
__global__ __launch_bounds__(256) void zgen(
    const float* __restrict__ x, const float* __restrict__ mix,
    u16* __restrict__ z) {
  const int gid = blockIdx.x * 256 + threadIdx.x;  // over M_ROWS*D/4 = 4,194,304
  const int dv = gid & 255;                        // float4 index within row
  const int n = (gid >> 8) & (SEQ_LEN - 1);
  const float4 xv = ((const float4*)x)[gid];
  float4 pv = make_float4(0.f, 0.f, 0.f, 0.f);
  if (n > 0) pv = ((const float4*)x)[gid - 256];   // previous token, same batch
  const float4 mv = ((const float4*)mix)[dv];
  ushort4 o;
  o.x = f2bf(xv.x + (pv.x - xv.x) * mv.x);
  o.y = f2bf(xv.y + (pv.y - xv.y) * mv.y);
  o.z = f2bf(xv.z + (pv.z - xv.z) * mv.z);
  o.w = f2bf(xv.w + (pv.w - xv.w) * mv.w);
  ((ushort4*)z)[gid] = o;
}

// ---------------- bf16 GEMM: out = A @ W^T, fused activation epilogue --------
// 128x128 tile, BK=32, 4 waves (2x2). Register-staged LDS (no global_load_lds
// this round -- the uintptr_t->AS(3) cast was crash suspect #1).
template <int ACT>
__global__ __launch_bounds__(256) void gemm_bt(
    const u16* __restrict__ A,   // [M][1024] bf16
    const u16* __restrict__ Bw,  // [1024][1024] bf16 row-major (torch W)
    void* __restrict__ outp,
    const u16* __restrict__ aux,     // kv for ACT_U, k for ACT_VMUL
    const float* __restrict__ bias) {  // for ACT_BIAS
  __shared__ __align__(16) u16 Al[128 * 32];
  __shared__ __align__(16) u16 Bl[128 * 32];
  const int tid = threadIdx.x;
  const int lane = tid & 63;
  const int wid = tid >> 6;
  const int m0 = blockIdx.x * 128;
  const int n0 = blockIdx.y * 128;
  const int wm = (wid >> 1) * 64;
  const int wn = (wid & 1) * 64;
  const int lr = lane & 15;
  const int lk = lane >> 4;

  // staging: thread t covers tile rows t/4 and t/4+64, cols (t%4)*8..+8
  // LDS byte offset tid*16 == row-major (tid>>2)*64B + (tid&3)*16B  (exact)
  const int srow = tid >> 2;
  const int scol = (tid & 3) * 8;
  const u16* ga0 = A + (size_t)(m0 + srow) * D_MODEL + scol;
  const u16* ga1 = ga0 + (size_t)64 * D_MODEL;
  const u16* gb0 = Bw + (size_t)(n0 + srow) * D_MODEL + scol;
  const u16* gb1 = gb0 + (size_t)64 * D_MODEL;
  uint4* lA0 = (uint4*)Al + tid;
  uint4* lA1 = (uint4*)Al + 256 + tid;
  uint4* lB0 = (uint4*)Bl + tid;
  uint4* lB1 = (uint4*)Bl + 256 + tid;

  f32x4 acc[4][4];
  const f32x4 z4 = {0.f, 0.f, 0.f, 0.f};
#pragma unroll
  for (int i = 0; i < 4; i++)
#pragma unroll
    for (int j = 0; j < 4; j++) acc[i][j] = z4;

  for (int kt = 0; kt < D_MODEL; kt += 32) {
    const uint4 a0 = *(const uint4*)(ga0 + kt);
    const uint4 a1 = *(const uint4*)(ga1 + kt);
    const uint4 b0 = *(const uint4*)(gb0 + kt);
    const uint4 b1 = *(const uint4*)(gb1 + kt);
    __syncthreads();  // all waves done reading previous tile
    *lA0 = a0; *lA1 = a1; *lB0 = b0; *lB1 = b1;
    __syncthreads();  // writes visible
    bf16x8 af[4], bfr[4];
#pragma unroll
    for (int i = 0; i < 4; i++) {
      af[i]  = *reinterpret_cast<const bf16x8*>(Al + (wm + i * 16 + lr) * 32 + lk * 8);
      bfr[i] = *reinterpret_cast<const bf16x8*>(Bl + (wn + i * 16 + lr) * 32 + lk * 8);
    }
#pragma unroll
    for (int i = 0; i < 4; i++)
#pragma unroll
      for (int j = 0; j < 4; j++)
        acc[i][j] = __builtin_amdgcn_mfma_f32_16x16x32_bf16(af[i], bfr[j], acc[i][j], 0, 0, 0);
  }

  // epilogue; C/D layout: col = lane&15, row = (lane>>4)*4 + e  [m89-verified]
#pragma unroll
  for (int i = 0; i < 4; i++) {
#pragma unroll
    for (int j = 0; j < 4; j++) {
#pragma unroll
      for (int e = 0; e < 4; e++) {
        const int row = m0 + wm + i * 16 + lk * 4 + e;
        const int col = n0 + wn + j * 16 + lr;
        const size_t idx = (size_t)row * D_MODEL + col;
        const float y = acc[i][j][e];
        if constexpr (ACT == ACT_DECAY) {
          ((float*)outp)[idx] = 1.f / (1.f + expf(y));  // exp(-softplus(y)) = sigmoid(-y)
        } else if constexpr (ACT == ACT_TANH) {
          ((u16*)outp)[idx] = f2bf(tanhf(y));
        } else if constexpr (ACT == ACT_VMUL) {
          ((u16*)outp)[idx] = f2bf(y * bf2f(aux[idx]));          // kv = v * k
        } else if constexpr (ACT == ACT_U) {
          ((u16*)outp)[idx] = f2bf(sigm(y) * bf2f(aux[idx]));    // u = alpha * kv
        } else if constexpr (ACT == ACT_SIG) {
          ((u16*)outp)[idx] = f2bf(sigm(y));
        } else {  // ACT_BIAS
          ((float*)outp)[idx] = y + bias[col];
        }
      }
    }
  }
}

// ---------------- chunked scan: state = state*decay + u; mixed = r*state -----
// pass1: per (chunk c, b, d) compute A=prod(decay), S=local state (zero carry-in)
__global__ __launch_bounds__(256) void scan1(
    const float* __restrict__ dec, const u16* __restrict__ u,
    float* __restrict__ Ac, float* __restrict__ Sc) {
  const int gid = blockIdx.x * 256 + threadIdx.x;  // c*4096 + b*1024 + d
  const int d = gid & 1023;
  const int b = (gid >> 10) & 3;
  const int c = gid >> 12;
  const size_t base = ((size_t)b * SEQ_LEN + (size_t)c * CHLEN) * D_MODEL + d;
  float A = 1.f, S = 0.f;
#pragma unroll 4
  for (int t = 0; t < CHLEN; t++) {
    const size_t off = base + (size_t)t * D_MODEL;
    const float dd = dec[off];
    S = S * dd + bf2f(u[off]);
    A *= dd;
  }
  Ac[gid] = A;
  Sc[gid] = S;
}

// pass2: sequential combine over chunks -> carry-in per chunk
__global__ __launch_bounds__(256) void scan2(
    const float* __restrict__ Ac, const float* __restrict__ Sc,
    float* __restrict__ In) {
  const int gid = blockIdx.x * 256 + threadIdx.x;  // b*1024 + d, 4096 total
  float carry = 0.f;
#pragma unroll 4
  for (int c = 0; c < NCHUNK; c++) {
    const int i = c * 4096 + gid;
    In[i] = carry;
    carry = carry * Ac[i] + Sc[i];
  }
}

// pass3: rescan with carry; mixed = r*state overwrites the decay buffer
__global__ __launch_bounds__(256) void scan3(
    float* __restrict__ decmix, const u16* __restrict__ u,
    const u16* __restrict__ r, const float* __restrict__ In) {
  const int gid = blockIdx.x * 256 + threadIdx.x;
  const int d = gid & 1023;
  const int b = (gid >> 10) & 3;
  const int c = gid >> 12;
  const size_t base = ((size_t)b * SEQ_LEN + (size_t)c * CHLEN) * D_MODEL + d;
  float state = In[gid];
#pragma unroll 4
  for (int t = 0; t < CHLEN; t++) {
    const size_t off = base + (size_t)t * D_MODEL;
    state = state * decmix[off] + bf2f(u[off]);
    decmix[off] = bf2f(r[off]) * state;  // read-before-write within thread: safe
  }
}

// ---------------- GroupNorm(H=16, 64ch) * g -> bf16 ---------------------------
__global__ __launch_bounds__(256) void gnorm(
    const float* __restrict__ mixed, const u16* __restrict__ g,
    const float* __restrict__ gw, const float* __restrict__ gb,
    u16* __restrict__ h) {
  const int wid = threadIdx.x >> 6;
  const int lane = threadIdx.x & 63;
  const int grp = blockIdx.x * 4 + wid;  // over M_ROWS*16 = 262144
  const int row = grp >> 4;
  const int hh = grp & 15;
  const int d = hh * 64 + lane;
  const size_t idx = (size_t)row * D_MODEL + d;
  const float v = mixed[idx];
  float s = v, s2 = v * v;
#pragma unroll
  for (int m = 32; m > 0; m >>= 1) {
    s += __shfl_xor(s, m, 64);
    s2 += __shfl_xor(s2, m, 64);
  }
  const float mu = s * (1.f / 64.f);
  float var = s2 * (1.f / 64.f) - mu * mu;
  const float inv = 1.f / sqrtf(var + GN_EPS_F);
  const float mn = (v - mu) * inv * gw[d] + gb[d];
  h[idx] = f2bf(mn * bf2f(g[idx]));
}

// ---------------- host ---------------------------------------------------------
extern "C" void kernel_launch(void* const* d_in, const int* in_sizes, int n_in,
                              void* d_out, int out_size, void* d_ws, size_t ws_size,
                              hipStream_t stream) {
  (void)in_sizes; (void)n_in; (void)out_size; (void)ws_size;
  const float* x    = (const float*)d_in[0];
  const float* mx_r = (const float*)d_in[1];
  const float* mx_w = (const float*)d_in[2];
  const float* mx_k = (const float*)d_in[3];
  const float* mx_v = (const float*)d_in[4];
  const float* mx_a = (const float*)d_in[5];
  const float* mx_g = (const float*)d_in[6];
  const float* W_r  = (const float*)d_in[7];
  const float* W_w  = (const float*)d_in[8];
  const float* W_k  = (const float*)d_in[9];
  const float* W_v  = (const float*)d_in[10];
  const float* W_a  = (const float*)d_in[11];
  const float* W_g  = (const float*)d_in[12];
  const float* W_o  = (const float*)d_in[13];
  const float* b_out = (const float*)d_in[14];
  const float* gn_w  = (const float*)d_in[15];
  const float* gn_b  = (const float*)d_in[16];

  // Workspace plan (209 MB total; buffers reused across phases):
  //   0   : Wb    14MB  (7x 1024x1024 bf16)
  //   14  : Ac     1MB
  //   15  : Sc     1MB
  //   16  : zbuf  32MB  (z bf16; later h = gnorm*g)
  //   48  : dec   64MB  (decay f32; scan3 overwrites with mixed f32)
  //   112 : ubuf  32MB  (u bf16)
  //   144 : kbuf  32MB  (k bf16; later r bf16)
  //   176 : vbuf  32MB  (kv bf16; later g bf16)
  //   208 : In     1MB
  char* ws = (char*)d_ws;
  const size_t MB = 1024ull * 1024ull;
  u16*   Wb   = (u16*)(ws);
  float* Ac   = (float*)(ws + 14 * MB);
  float* Sc   = (float*)(ws + 15 * MB);
  u16*   zbuf = (u16*)(ws + 16 * MB);
  float* dec  = (float*)(ws + 48 * MB);
  u16*   ubuf = (u16*)(ws + 112 * MB);
  u16*   kbuf = (u16*)(ws + 144 * MB);
  u16*   vbuf = (u16*)(ws + 176 * MB);
  float* Inb  = (float*)(ws + 208 * MB);

  wconv<<<7168, 256, 0, stream>>>(W_r, W_w, W_k, W_v, W_a, W_g, W_o, Wb);

  const dim3 gg(128, 8);
  // decay = sigmoid(-lin_w), f32
  zgen<<<16384, 256, 0, stream>>>(x, mx_w, zbuf);
  gemm_bt<ACT_DECAY><<<gg, 256, 0, stream>>>(zbuf, Wb + 1 * 1048576, dec, nullptr, nullptr);
  // k = tanh -> kbuf
  zgen<<<16384, 256, 0, stream>>>(x, mx_k, zbuf);
  gemm_bt<ACT_TANH><<<gg, 256, 0, stream>>>(zbuf, Wb + 2 * 1048576, kbuf, nullptr, nullptr);
  // kv = v * k -> vbuf  (kbuf free after next step consumes nothing further)
  zgen<<<16384, 256, 0, stream>>>(x, mx_v, zbuf);
  gemm_bt<ACT_VMUL><<<gg, 256, 0, stream>>>(zbuf, Wb + 3 * 1048576, vbuf, kbuf, nullptr);
  // u = sigmoid(lin_a) * kv -> ubuf (bf16)
  zgen<<<16384, 256, 0, stream>>>(x, mx_a, zbuf);
  gemm_bt<ACT_U><<<gg, 256, 0, stream>>>(zbuf, Wb + 4 * 1048576, ubuf, vbuf, nullptr);
  // r = sigmoid -> kbuf (reuse)
  zgen<<<16384, 256, 0, stream>>>(x, mx_r, zbuf);
  gemm_bt<ACT_SIG><<<gg, 256, 0, stream>>>(zbuf, Wb + 0, kbuf, nullptr, nullptr);
  // g = sigmoid -> vbuf (reuse)
  zgen<<<16384, 256, 0, stream>>>(x, mx_g, zbuf);
  gemm_bt<ACT_SIG><<<gg, 256, 0, stream>>>(zbuf, Wb + 5 * 1048576, vbuf, nullptr, nullptr);

  // recurrence (chunked parallel scan); mixed overwrites dec in scan3
  scan1<<<1024, 256, 0, stream>>>(dec, ubuf, Ac, Sc);
  scan2<<<16, 256, 0, stream>>>(Ac, Sc, Inb);
  scan3<<<1024, 256, 0, stream>>>(dec, ubuf, kbuf, Inb);

  // groupnorm(mixed) * g -> h (bf16, into zbuf)
  gnorm<<<65536, 256, 0, stream>>>(dec, vbuf, gn_w, gn_b, zbuf);

  // out = h @ W_out^T + b_out, f32
  gemm_bt<ACT_BIAS><<<gg, 256, 0, stream>>>(zbuf, Wb + 6 * 1048576, (float*)d_out, nullptr, b_out);
}

// Round 3
// 688.840 us; speedup vs baseline: 1.0038x; 1.0038x over previous
//
#include <hip/hip_runtime.h>
#include <cstdint>
#include <cstddef>

#define D_MODEL 1024
#define SEQ_LEN 4096
#define NBATCH  4
#define M_ROWS  (NBATCH * SEQ_LEN)   // 16384 rows (b*4096+n)
#define NCHUNK  64
#define CHLEN   64                   // SEQ_LEN / NCHUNK
#define GN_EPS_F 0.00064f

typedef unsigned short u16;
typedef __attribute__((ext_vector_type(4))) float f32x4;
typedef __attribute__((ext_vector_type(8))) __bf16 bf16x8;

enum { ACT_DECAY = 0, ACT_TANH, ACT_VMUL, ACT_U, ACT_SIG, ACT_BIAS };

__device__ __forceinline__ u16 f2bf(float f) {
  union { float f; uint32_t u; } un; un.f = f;
  uint32_t r = (un.u + 0x7FFFu + ((un.u >> 16) & 1u)) >> 16;  // RNE
  return (u16)r;
}
__device__ __forceinline__ float bf2f(u16 h) {
  union { uint32_t u; float f; } un; un.u = ((uint32_t)h) << 16;
  return un.f;
}
__device__ __forceinline__ float sigm(float y) { return 1.f / (1.f + expf(-y)); }

// async global->LDS, 16B/lane. Direct addrspacecast (no int round-trip).
// LDS dst must be the WAVE-UNIFORM base; HW adds lane*16. Global src is per-lane.
__device__ __forceinline__ void load_lds16(const u16* g, u16* l) {
  __builtin_amdgcn_global_load_lds(
      (const __attribute__((address_space(1))) void*)g,
      (__attribute__((address_space(3))) void*)l, 16, 0, 0);
}

// ---------------- weights f32 -> bf16 (7 matrices, contiguous slots) ----------
__global__ __launch_bounds__(256) void wconv(
    const float* __restrict__ w0, const float* __restrict__ w1,
    const float* __restrict__ w2, const float* __restrict__ w3,
    const float* __restrict__ w4, const float* __restrict__ w5,
    const float* __restrict__ w6, u16* __restrict__ Wb) {
  const int gid = blockIdx.x * 256 + threadIdx.x;  // over 7*262144 float4s
  const int m = gid >> 18;
  const int off = gid & 262143;
  const float* src;
  switch (m) {
    case 0: src = w0; break; case 1: src = w1; break; case 2: src = w2; break;
    case 3: src = w3; break; case 4: src = w4; break; case 5: src = w5; break;
    default: src = w6; break;
  }
  const float4 v = ((const float4*)src)[off];
  ushort4 o;
  o.x = f2bf(v.x); o.y = f2bf(v.y); o.z = f2bf(v.z); o.w = f2bf(v.w);
  ((ushort4*)Wb)[gid] = o;
}

// ---------------- z = x + (prev - x) * mix  -> bf16 ---------------------------
__global__ __launch_bounds__(256) void zgen(
    const float* __restrict__ x, const float* __restrict__ mix,
    u16* __restrict__ z) {
  const int gid = blockIdx.x * 256 + threadIdx.x;  // over M_ROWS*D/4 = 4,194,304
  const int dv = gid & 255;                        // float4 index within row
  const int n = (gid >> 8) & (SEQ_LEN - 1);
  const float4 xv = ((const float4*)x)[gid];
  float4 pv = make_float4(0.f, 0.f, 0.f, 0.f);
  if (n > 0) pv = ((const float4*)x)[gid - 256];   // previous token, same batch
  const float4 mv = ((const float4*)mix)[dv];
  ushort4 o;
  o.x = f2bf(xv.x + (pv.x - xv.x) * mv.x);
  o.y = f2bf(xv.y + (pv.y - xv.y) * mv.y);
  o.z = f2bf(xv.z + (pv.z - xv.z) * mv.z);
  o.w = f2bf(xv.w + (pv.w - xv.w) * mv.w);
  ((ushort4*)z)[gid] = o;
}

// ---------------- bf16 GEMM: out = A @ W^T, fused activation epilogue --------
// m97 structure: 128x128 tile, BK=32, 4 waves (2x2), global_load_lds width 16,
// 2-barrier K-loop. Grid is (N/128, M/128): n-fastest dispatch -> consecutive
// blocks share the A-panel (L2 reuse).
template <int ACT>
__global__ __launch_bounds__(256) void gemm_bt(
    const u16* __restrict__ A,   // [M][1024] bf16
    const u16* __restrict__ Bw,  // [1024][1024] bf16 row-major (torch W)
    void* __restrict__ outp,
    const u16* __restrict__ aux,     // kv for ACT_U, k for ACT_VMUL
    const float* __restrict__ bias) {  // for ACT_BIAS
  __shared__ __align__(16) u16 Al[128 * 32];
  __shared__ __align__(16) u16 Bl[128 * 32];
  const int tid = threadIdx.x;
  const int lane = tid & 63;
  const int wid = tid >> 6;
  const int m0 = blockIdx.y * 128;
  const int n0 = blockIdx.x * 128;
  const int wm = (wid >> 1) * 64;
  const int wn = (wid & 1) * 64;
  const int lr = lane & 15;
  const int lk = lane >> 4;

  // staging: wave w stages rows w*16..w*16+15 (and +64) of each tile;
  // lane i: row = w*16 + i/4, col = (i%4)*8. LDS dst base wave-uniform.
  const int srow = tid >> 2;           // == wid*16 + (lane>>2)
  const int scol = (tid & 3) * 8;
  const u16* ga0 = A + (size_t)(m0 + srow) * D_MODEL + scol;
  const u16* ga1 = ga0 + (size_t)64 * D_MODEL;
  const u16* gb0 = Bw + (size_t)(n0 + srow) * D_MODEL + scol;
  const u16* gb1 = gb0 + (size_t)64 * D_MODEL;
  u16* la0 = Al + wid * 512;           // wave-uniform LDS bases (1KB per wave)
  u16* la1 = Al + 2048 + wid * 512;
  u16* lb0 = Bl + wid * 512;
  u16* lb1 = Bl + 2048 + wid * 512;

  f32x4 acc[4][4];
  const f32x4 z4 = {0.f, 0.f, 0.f, 0.f};
#pragma unroll
  for (int i = 0; i < 4; i++)
#pragma unroll
    for (int j = 0; j < 4; j++) acc[i][j] = z4;

  for (int kt = 0; kt < D_MODEL; kt += 32) {
    load_lds16(ga0 + kt, la0);
    load_lds16(ga1 + kt, la1);
    load_lds16(gb0 + kt, lb0);
    load_lds16(gb1 + kt, lb1);
    __syncthreads();  // compiler drains vmcnt before s_barrier -> tiles ready
    bf16x8 af[4], bfr[4];
#pragma unroll
    for (int i = 0; i < 4; i++) {
      af[i]  = *reinterpret_cast<const bf16x8*>(Al + (wm + i * 16 + lr) * 32 + lk * 8);
      bfr[i] = *reinterpret_cast<const bf16x8*>(Bl + (wn + i * 16 + lr) * 32 + lk * 8);
    }
#pragma unroll
    for (int i = 0; i < 4; i++)
#pragma unroll
      for (int j = 0; j < 4; j++)
        acc[i][j] = __builtin_amdgcn_mfma_f32_16x16x32_bf16(af[i], bfr[j], acc[i][j], 0, 0, 0);
    __syncthreads();  // reads done before next iteration's staging
  }

  // epilogue; C/D layout: col = lane&15, row = (lane>>4)*4 + e  [m89-verified]
#pragma unroll
  for (int i = 0; i < 4; i++) {
#pragma unroll
    for (int j = 0; j < 4; j++) {
#pragma unroll
      for (int e = 0; e < 4; e++) {
        const int row = m0 + wm + i * 16 + lk * 4 + e;
        const int col = n0 + wn + j * 16 + lr;
        const size_t idx = (size_t)row * D_MODEL + col;
        const float y = acc[i][j][e];
        if constexpr (ACT == ACT_DECAY) {
          ((float*)outp)[idx] = 1.f / (1.f + expf(y));  // exp(-softplus(y)) = sigmoid(-y)
        } else if constexpr (ACT == ACT_TANH) {
          ((u16*)outp)[idx] = f2bf(tanhf(y));
        } else if constexpr (ACT == ACT_VMUL) {
          ((u16*)outp)[idx] = f2bf(y * bf2f(aux[idx]));          // kv = v * k
        } else if constexpr (ACT == ACT_U) {
          ((u16*)outp)[idx] = f2bf(sigm(y) * bf2f(aux[idx]));    // u = alpha * kv
        } else if constexpr (ACT == ACT_SIG) {
          ((u16*)outp)[idx] = f2bf(sigm(y));
        } else {  // ACT_BIAS
          ((float*)outp)[idx] = y + bias[col];
        }
      }
    }
  }
}

// ---------------- chunked scan: state = state*decay + u; mixed = r*state -----
__global__ __launch_bounds__(256) void scan1(
    const float* __restrict__ dec, const u16* __restrict__ u,
    float* __restrict__ Ac, float* __restrict__ Sc) {
  const int gid = blockIdx.x * 256 + threadIdx.x;  // c*4096 + b*1024 + d
  const int d = gid & 1023;
  const int b = (gid >> 10) & 3;
  const int c = gid >> 12;
  const size_t base = ((size_t)b * SEQ_LEN + (size_t)c * CHLEN) * D_MODEL + d;
  float A = 1.f, S = 0.f;
#pragma unroll 4
  for (int t = 0; t < CHLEN; t++) {
    const size_t off = base + (size_t)t * D_MODEL;
    const float dd = dec[off];
    S = S * dd + bf2f(u[off]);
    A *= dd;
  }
  Ac[gid] = A;
  Sc[gid] = S;
}

__global__ __launch_bounds__(256) void scan2(
    const float* __restrict__ Ac, const float* __restrict__ Sc,
    float* __restrict__ In) {
  const int gid = blockIdx.x * 256 + threadIdx.x;  // b*1024 + d, 4096 total
  float carry = 0.f;
#pragma unroll 4
  for (int c = 0; c < NCHUNK; c++) {
    const int i = c * 4096 + gid;
    In[i] = carry;
    carry = carry * Ac[i] + Sc[i];
  }
}

__global__ __launch_bounds__(256) void scan3(
    float* __restrict__ decmix, const u16* __restrict__ u,
    const u16* __restrict__ r, const float* __restrict__ In) {
  const int gid = blockIdx.x * 256 + threadIdx.x;
  const int d = gid & 1023;
  const int b = (gid >> 10) & 3;
  const int c = gid >> 12;
  const size_t base = ((size_t)b * SEQ_LEN + (size_t)c * CHLEN) * D_MODEL + d;
  float state = In[gid];
#pragma unroll 4
  for (int t = 0; t < CHLEN; t++) {
    const size_t off = base + (size_t)t * D_MODEL;
    state = state * decmix[off] + bf2f(u[off]);
    decmix[off] = bf2f(r[off]) * state;  // read-before-write within thread: safe
  }
}

// ---------------- GroupNorm(H=16, 64ch) * g -> bf16 ---------------------------
__global__ __launch_bounds__(256) void gnorm(
    const float* __restrict__ mixed, const u16* __restrict__ g,
    const float* __restrict__ gw, const float* __restrict__ gb,
    u16* __restrict__ h) {
  const int wid = threadIdx.x >> 6;
  const int lane = threadIdx.x & 63;
  const int grp = blockIdx.x * 4 + wid;  // over M_ROWS*16 = 262144
  const int row = grp >> 4;
  const int hh = grp & 15;
  const int d = hh * 64 + lane;
  const size_t idx = (size_t)row * D_MODEL + d;
  const float v = mixed[idx];
  float s = v, s2 = v * v;
#pragma unroll
  for (int m = 32; m > 0; m >>= 1) {
    s += __shfl_xor(s, m, 64);
    s2 += __shfl_xor(s2, m, 64);
  }
  const float mu = s * (1.f / 64.f);
  float var = s2 * (1.f / 64.f) - mu * mu;
  const float inv = 1.f / sqrtf(var + GN_EPS_F);
  const float mn = (v - mu) * inv * gw[d] + gb[d];
  h[idx] = f2bf(mn * bf2f(g[idx]));
}

// ---------------- host ---------------------------------------------------------
extern "C" void kernel_launch(void* const* d_in, const int* in_sizes, int n_in,
                              void* d_out, int out_size, void* d_ws, size_t ws_size,
                              hipStream_t stream) {
  (void)in_sizes; (void)n_in; (void)out_size; (void)ws_size;
  const float* x    = (const float*)d_in[0];
  const float* mx_r = (const float*)d_in[1];
  const float* mx_w = (const float*)d_in[2];
  const float* mx_k = (const float*)d_in[3];
  const float* mx_v = (const float*)d_in[4];
  const float* mx_a = (const float*)d_in[5];
  const float* mx_g = (const float*)d_in[6];
  const float* W_r  = (const float*)d_in[7];
  const float* W_w  = (const float*)d_in[8];
  const float* W_k  = (const float*)d_in[9];
  const float* W_v  = (const float*)d_in[10];
  const float* W_a  = (const float*)d_in[11];
  const float* W_g  = (const float*)d_in[12];
  const float* W_o  = (const float*)d_in[13];
  const float* b_out = (const float*)d_in[14];
  const float* gn_w  = (const float*)d_in[15];
  const float* gn_b  = (const float*)d_in[16];

  // Workspace plan (209 MB total; buffers reused across phases):
  //   0   : Wb    14MB  (7x 1024x1024 bf16)
  //   14  : Ac     1MB
  //   15  : Sc     1MB
  //   16  : zbuf  32MB  (z bf16; later h = gnorm*g)
  //   48  : dec   64MB  (decay f32; scan3 overwrites with mixed f32)
  //   112 : ubuf  32MB  (u bf16)
  //   144 : kbuf  32MB  (k bf16; later r bf16)
  //   176 : vbuf  32MB  (kv bf16; later g bf16)
  //   208 : In     1MB
  char* ws = (char*)d_ws;
  const size_t MB = 1024ull * 1024ull;
  u16*   Wb   = (u16*)(ws);
  float* Ac   = (float*)(ws + 14 * MB);
  float* Sc   = (float*)(ws + 15 * MB);
  u16*   zbuf = (u16*)(ws + 16 * MB);
  float* dec  = (float*)(ws + 48 * MB);
  u16*   ubuf = (u16*)(ws + 112 * MB);
  u16*   kbuf = (u16*)(ws + 144 * MB);
  u16*   vbuf = (u16*)(ws + 176 * MB);
  float* Inb  = (float*)(ws + 208 * MB);

  wconv<<<7168, 256, 0, stream>>>(W_r, W_w, W_k, W_v, W_a, W_g, W_o, Wb);

  const dim3 gg(8, 128);  // (N/128, M/128): n-fastest -> A-panel L2 reuse
  // decay = sigmoid(-lin_w), f32
  zgen<<<16384, 256, 0, stream>>>(x, mx_w, zbuf);
  gemm_bt<ACT_DECAY><<<gg, 256, 0, stream>>>(zbuf, Wb + 1 * 1048576, dec, nullptr, nullptr);
  // k = tanh -> kbuf
  zgen<<<16384, 256, 0, stream>>>(x, mx_k, zbuf);
  gemm_bt<ACT_TANH><<<gg, 256, 0, stream>>>(zbuf, Wb + 2 * 1048576, kbuf, nullptr, nullptr);
  // kv = v * k -> vbuf
  zgen<<<16384, 256, 0, stream>>>(x, mx_v, zbuf);
  gemm_bt<ACT_VMUL><<<gg, 256, 0, stream>>>(zbuf, Wb + 3 * 1048576, vbuf, kbuf, nullptr);
  // u = sigmoid(lin_a) * kv -> ubuf (bf16)
  zgen<<<16384, 256, 0, stream>>>(x, mx_a, zbuf);
  gemm_bt<ACT_U><<<gg, 256, 0, stream>>>(zbuf, Wb + 4 * 1048576, ubuf, vbuf, nullptr);
  // r = sigmoid -> kbuf (reuse)
  zgen<<<16384, 256, 0, stream>>>(x, mx_r, zbuf);
  gemm_bt<ACT_SIG><<<gg, 256, 0, stream>>>(zbuf, Wb + 0, kbuf, nullptr, nullptr);
  // g = sigmoid -> vbuf (reuse)
  zgen<<<16384, 256, 0, stream>>>(x, mx_g, zbuf);
  gemm_bt<ACT_SIG><<<gg, 256, 0, stream>>>(zbuf, Wb + 5 * 1048576, vbuf, nullptr, nullptr);

  // recurrence (chunked parallel scan); mixed overwrites dec in scan3
  scan1<<<1024, 256, 0, stream>>>(dec, ubuf, Ac, Sc);
  scan2<<<16, 256, 0, stream>>>(Ac, Sc, Inb);
  scan3<<<1024, 256, 0, stream>>>(dec, ubuf, kbuf, Inb);

  // groupnorm(mixed) * g -> h (bf16, into zbuf)
  gnorm<<<65536, 256, 0, stream>>>(dec, vbuf, gn_w, gn_b, zbuf);

  // out = h @ W_out^T + b_out, f32
  gemm_bt<ACT_BIAS><<<gg, 256, 0, stream>>>(zbuf, Wb + 6 * 1048576, (float*)d_out, nullptr, b_out);
}

// Round 4
// 668.314 us; speedup vs baseline: 1.0346x; 1.0307x over previous
//
#include <hip/hip_runtime.h>
#include <cstdint>
#include <cstddef>

#define D_MODEL 1024
#define SEQ_LEN 4096
#define NBATCH  4
#define M_ROWS  (NBATCH * SEQ_LEN)   // 16384 rows (b*4096+n)
#define NCHUNK  64
#define CHLEN   64                   // SEQ_LEN / NCHUNK
#define GN_EPS_F 0.00064f

typedef unsigned short u16;
typedef __attribute__((ext_vector_type(4))) float f32x4;
typedef __attribute__((ext_vector_type(8))) __bf16 bf16x8;

enum { ACT_DECAY = 0, ACT_TANH, ACT_VMUL, ACT_U, ACT_SIG, ACT_BIAS };

__device__ __forceinline__ u16 f2bf(float f) {
  union { float f; uint32_t u; } un; un.f = f;
  uint32_t r = (un.u + 0x7FFFu + ((un.u >> 16) & 1u)) >> 16;  // RNE
  return (u16)r;
}
__device__ __forceinline__ float bf2f(u16 h) {
  union { uint32_t u; float f; } un; un.u = ((uint32_t)h) << 16;
  return un.f;
}
__device__ __forceinline__ float sigm(float y) { return 1.f / (1.f + expf(-y)); }

// async global->LDS, 16B/lane. LDS dst = wave-uniform base (HW adds lane*16).
__device__ __forceinline__ void load_lds16(const u16* g, u16* l) {
  __builtin_amdgcn_global_load_lds(
      (const __attribute__((address_space(1))) void*)g,
      (__attribute__((address_space(3))) void*)l, 16, 0, 0);
}

// ---------------- weights f32 -> bf16 (7 matrices, contiguous slots) ----------
__global__ __launch_bounds__(256) void wconv(
    const float* __restrict__ w0, const float* __restrict__ w1,
    const float* __restrict__ w2, const float* __restrict__ w3,
    const float* __restrict__ w4, const float* __restrict__ w5,
    const float* __restrict__ w6, u16* __restrict__ Wb) {
  const int gid = blockIdx.x * 256 + threadIdx.x;  // over 7*262144 float4s
  const int m = gid >> 18;
  const int off = gid & 262143;
  const float* src;
  switch (m) {
    case 0: src = w0; break; case 1: src = w1; break; case 2: src = w2; break;
    case 3: src = w3; break; case 4: src = w4; break; case 5: src = w5; break;
    default: src = w6; break;
  }
  const float4 v = ((const float4*)src)[off];
  ushort4 o;
  o.x = f2bf(v.x); o.y = f2bf(v.y); o.z = f2bf(v.z); o.w = f2bf(v.w);
  ((ushort4*)Wb)[gid] = o;
}

// ---------------- z = x + (prev - x) * mix  -> bf16 ---------------------------
__global__ __launch_bounds__(256) void zgen(
    const float* __restrict__ x, const float* __restrict__ mix,
    u16* __restrict__ z) {
  const int gid = blockIdx.x * 256 + threadIdx.x;  // over M_ROWS*D/4 = 4,194,304
  const int dv = gid & 255;                        // float4 index within row
  const int n = (gid >> 8) & (SEQ_LEN - 1);
  const float4 xv = ((const float4*)x)[gid];
  float4 pv = make_float4(0.f, 0.f, 0.f, 0.f);
  if (n > 0) pv = ((const float4*)x)[gid - 256];   // previous token, same batch
  const float4 mv = ((const float4*)mix)[dv];
  ushort4 o;
  o.x = f2bf(xv.x + (pv.x - xv.x) * mv.x);
  o.y = f2bf(xv.y + (pv.y - xv.y) * mv.y);
  o.z = f2bf(xv.z + (pv.z - xv.z) * mv.z);
  o.w = f2bf(xv.w + (pv.w - xv.w) * mv.w);
  ((ushort4*)z)[gid] = o;
}

// ---------------- bf16 GEMM: out = A @ W^T, fused activation epilogue --------
// 128x128 tile, BK=32, 4 waves (2x2), global_load_lds width 16.
// 2-phase double-buffered pipeline: STAGE(t+1) issued BEFORE compute(t), one
// __syncthreads per iter (its implicit vmcnt(0)/lgkmcnt(0) drain covers both
// the prefetch completion and the LDS-read completion). Chunked XCD swizzle:
// each XCD owns 16 complete A-panels (all 8 n-tiles) -> A fetched by one L2.
template <int ACT>
__global__ __launch_bounds__(256) void gemm_bt(
    const u16* __restrict__ A,   // [M][1024] bf16
    const u16* __restrict__ Bw,  // [1024][1024] bf16 row-major (torch W)
    void* __restrict__ outp,
    const u16* __restrict__ aux,     // kv for ACT_U, k for ACT_VMUL
    const float* __restrict__ bias) {  // for ACT_BIAS
  __shared__ __align__(16) u16 Al[2][128 * 32];
  __shared__ __align__(16) u16 Bl[2][128 * 32];
  const int tid = threadIdx.x;
  const int lane = tid & 63;
  const int wid = tid >> 6;

  // chunked XCD swizzle: bid%8 = XCD (empirical round-robin); give each XCD a
  // contiguous run of 128 logical tiles = 16 m-panels x 8 n-tiles.
  const int bid = blockIdx.x;                  // 0..1023
  const int swz = (bid & 7) * 128 + (bid >> 3);
  const int m0 = (swz >> 3) * 128;
  const int n0 = (swz & 7) * 128;

  const int wm = (wid >> 1) * 64;
  const int wn = (wid & 1) * 64;
  const int lr = lane & 15;
  const int lk = lane >> 4;

  // staging: wave w stages rows w*16..w*16+15 (and +64) of each tile;
  // lane i: row = w*16 + i/4, col = (i%4)*8; LDS chunk byte i*16 matches.
  const int srow = tid >> 2;
  const int scol = (tid & 3) * 8;
  const u16* ga0 = A + (size_t)(m0 + srow) * D_MODEL + scol;
  const u16* ga1 = ga0 + (size_t)64 * D_MODEL;
  const u16* gb0 = Bw + (size_t)(n0 + srow) * D_MODEL + scol;
  const u16* gb1 = gb0 + (size_t)64 * D_MODEL;

  f32x4 acc[4][4];
  const f32x4 z4 = {0.f, 0.f, 0.f, 0.f};
#pragma unroll
  for (int i = 0; i < 4; i++)
#pragma unroll
    for (int j = 0; j < 4; j++) acc[i][j] = z4;

  // prologue: stage tile 0 into buffer 0
  load_lds16(ga0, &Al[0][wid * 512]);
  load_lds16(ga1, &Al[0][2048 + wid * 512]);
  load_lds16(gb0, &Bl[0][wid * 512]);
  load_lds16(gb1, &Bl[0][2048 + wid * 512]);
  __syncthreads();

  int cur = 0;
  for (int kt = 0; kt < D_MODEL; kt += 32) {
    // issue next tile's loads into the other buffer BEFORE computing
    if (kt + 32 < D_MODEL) {
      const int nb = cur ^ 1;
      load_lds16(ga0 + kt + 32, &Al[nb][wid * 512]);
      load_lds16(ga1 + kt + 32, &Al[nb][2048 + wid * 512]);
      load_lds16(gb0 + kt + 32, &Bl[nb][wid * 512]);
      load_lds16(gb1 + kt + 32, &Bl[nb][2048 + wid * 512]);
    }
    bf16x8 af[4], bfr[4];
#pragma unroll
    for (int i = 0; i < 4; i++) {
      af[i]  = *reinterpret_cast<const bf16x8*>(&Al[cur][(wm + i * 16 + lr) * 32 + lk * 8]);
      bfr[i] = *reinterpret_cast<const bf16x8*>(&Bl[cur][(wn + i * 16 + lr) * 32 + lk * 8]);
    }
#pragma unroll
    for (int i = 0; i < 4; i++)
#pragma unroll
      for (int j = 0; j < 4; j++)
        acc[i][j] = __builtin_amdgcn_mfma_f32_16x16x32_bf16(af[i], bfr[j], acc[i][j], 0, 0, 0);
    __syncthreads();  // prefetch landed + all reads of buf[cur] done
    cur ^= 1;
  }

  // epilogue; C/D layout: col = lane&15, row = (lane>>4)*4 + e  [m89-verified]
#pragma unroll
  for (int i = 0; i < 4; i++) {
#pragma unroll
    for (int j = 0; j < 4; j++) {
#pragma unroll
      for (int e = 0; e < 4; e++) {
        const int row = m0 + wm + i * 16 + lk * 4 + e;
        const int col = n0 + wn + j * 16 + lr;
        const size_t idx = (size_t)row * D_MODEL + col;
        const float y = acc[i][j][e];
        if constexpr (ACT == ACT_DECAY) {
          ((float*)outp)[idx] = 1.f / (1.f + expf(y));  // exp(-softplus(y)) = sigmoid(-y)
        } else if constexpr (ACT == ACT_TANH) {
          ((u16*)outp)[idx] = f2bf(tanhf(y));
        } else if constexpr (ACT == ACT_VMUL) {
          ((u16*)outp)[idx] = f2bf(y * bf2f(aux[idx]));          // kv = v * k
        } else if constexpr (ACT == ACT_U) {
          ((u16*)outp)[idx] = f2bf(sigm(y) * bf2f(aux[idx]));    // u = alpha * kv
        } else if constexpr (ACT == ACT_SIG) {
          ((u16*)outp)[idx] = f2bf(sigm(y));
        } else {  // ACT_BIAS
          ((float*)outp)[idx] = y + bias[col];
        }
      }
    }
  }
}

// ---------------- chunked scan: state = state*decay + u; mixed = r*state -----
__global__ __launch_bounds__(256) void scan1(
    const float* __restrict__ dec, const u16* __restrict__ u,
    float* __restrict__ Ac, float* __restrict__ Sc) {
  const int gid = blockIdx.x * 256 + threadIdx.x;  // c*4096 + b*1024 + d
  const int d = gid & 1023;
  const int b = (gid >> 10) & 3;
  const int c = gid >> 12;
  const size_t base = ((size_t)b * SEQ_LEN + (size_t)c * CHLEN) * D_MODEL + d;
  float A = 1.f, S = 0.f;
#pragma unroll 4
  for (int t = 0; t < CHLEN; t++) {
    const size_t off = base + (size_t)t * D_MODEL;
    const float dd = dec[off];
    S = S * dd + bf2f(u[off]);
    A *= dd;
  }
  Ac[gid] = A;
  Sc[gid] = S;
}

__global__ __launch_bounds__(256) void scan2(
    const float* __restrict__ Ac, const float* __restrict__ Sc,
    float* __restrict__ In) {
  const int gid = blockIdx.x * 256 + threadIdx.x;  // b*1024 + d, 4096 total
  float carry = 0.f;
#pragma unroll 4
  for (int c = 0; c < NCHUNK; c++) {
    const int i = c * 4096 + gid;
    In[i] = carry;
    carry = carry * Ac[i] + Sc[i];
  }
}

__global__ __launch_bounds__(256) void scan3(
    float* __restrict__ decmix, const u16* __restrict__ u,
    const u16* __restrict__ r, const float* __restrict__ In) {
  const int gid = blockIdx.x * 256 + threadIdx.x;
  const int d = gid & 1023;
  const int b = (gid >> 10) & 3;
  const int c = gid >> 12;
  const size_t base = ((size_t)b * SEQ_LEN + (size_t)c * CHLEN) * D_MODEL + d;
  float state = In[gid];
#pragma unroll 4
  for (int t = 0; t < CHLEN; t++) {
    const size_t off = base + (size_t)t * D_MODEL;
    state = state * decmix[off] + bf2f(u[off]);
    decmix[off] = bf2f(r[off]) * state;  // read-before-write within thread: safe
  }
}

// ---------------- GroupNorm(H=16, 64ch) * g -> bf16 ---------------------------
__global__ __launch_bounds__(256) void gnorm(
    const float* __restrict__ mixed, const u16* __restrict__ g,
    const float* __restrict__ gw, const float* __restrict__ gb,
    u16* __restrict__ h) {
  const int wid = threadIdx.x >> 6;
  const int lane = threadIdx.x & 63;
  const int grp = blockIdx.x * 4 + wid;  // over M_ROWS*16 = 262144
  const int row = grp >> 4;
  const int hh = grp & 15;
  const int d = hh * 64 + lane;
  const size_t idx = (size_t)row * D_MODEL + d;
  const float v = mixed[idx];
  float s = v, s2 = v * v;
#pragma unroll
  for (int m = 32; m > 0; m >>= 1) {
    s += __shfl_xor(s, m, 64);
    s2 += __shfl_xor(s2, m, 64);
  }
  const float mu = s * (1.f / 64.f);
  float var = s2 * (1.f / 64.f) - mu * mu;
  const float inv = 1.f / sqrtf(var + GN_EPS_F);
  const float mn = (v - mu) * inv * gw[d] + gb[d];
  h[idx] = f2bf(mn * bf2f(g[idx]));
}

// ---------------- host ---------------------------------------------------------
extern "C" void kernel_launch(void* const* d_in, const int* in_sizes, int n_in,
                              void* d_out, int out_size, void* d_ws, size_t ws_size,
                              hipStream_t stream) {
  (void)in_sizes; (void)n_in; (void)out_size; (void)ws_size;
  const float* x    = (const float*)d_in[0];
  const float* mx_r = (const float*)d_in[1];
  const float* mx_w = (const float*)d_in[2];
  const float* mx_k = (const float*)d_in[3];
  const float* mx_v = (const float*)d_in[4];
  const float* mx_a = (const float*)d_in[5];
  const float* mx_g = (const float*)d_in[6];
  const float* W_r  = (const float*)d_in[7];
  const float* W_w  = (const float*)d_in[8];
  const float* W_k  = (const float*)d_in[9];
  const float* W_v  = (const float*)d_in[10];
  const float* W_a  = (const float*)d_in[11];
  const float* W_g  = (const float*)d_in[12];
  const float* W_o  = (const float*)d_in[13];
  const float* b_out = (const float*)d_in[14];
  const float* gn_w  = (const float*)d_in[15];
  const float* gn_b  = (const float*)d_in[16];

  // Workspace plan (209 MB total; buffers reused across phases):
  //   0   : Wb    14MB | 14: Ac 1MB | 15: Sc 1MB | 16: zbuf 32MB (z; later h)
  //   48  : dec   64MB (decay f32; scan3 overwrites with mixed f32)
  //   112 : ubuf  32MB (u bf16) | 144: kbuf 32MB (k; later r)
  //   176 : vbuf  32MB (kv; later g) | 208: In 1MB
  char* ws = (char*)d_ws;
  const size_t MB = 1024ull * 1024ull;
  u16*   Wb   = (u16*)(ws);
  float* Ac   = (float*)(ws + 14 * MB);
  float* Sc   = (float*)(ws + 15 * MB);
  u16*   zbuf = (u16*)(ws + 16 * MB);
  float* dec  = (float*)(ws + 48 * MB);
  u16*   ubuf = (u16*)(ws + 112 * MB);
  u16*   kbuf = (u16*)(ws + 144 * MB);
  u16*   vbuf = (u16*)(ws + 176 * MB);
  float* Inb  = (float*)(ws + 208 * MB);

  wconv<<<7168, 256, 0, stream>>>(W_r, W_w, W_k, W_v, W_a, W_g, W_o, Wb);

  // decay = sigmoid(-lin_w), f32
  zgen<<<16384, 256, 0, stream>>>(x, mx_w, zbuf);
  gemm_bt<ACT_DECAY><<<1024, 256, 0, stream>>>(zbuf, Wb + 1 * 1048576, dec, nullptr, nullptr);
  // k = tanh -> kbuf
  zgen<<<16384, 256, 0, stream>>>(x, mx_k, zbuf);
  gemm_bt<ACT_TANH><<<1024, 256, 0, stream>>>(zbuf, Wb + 2 * 1048576, kbuf, nullptr, nullptr);
  // kv = v * k -> vbuf
  zgen<<<16384, 256, 0, stream>>>(x, mx_v, zbuf);
  gemm_bt<ACT_VMUL><<<1024, 256, 0, stream>>>(zbuf, Wb + 3 * 1048576, vbuf, kbuf, nullptr);
  // u = sigmoid(lin_a) * kv -> ubuf (bf16)
  zgen<<<16384, 256, 0, stream>>>(x, mx_a, zbuf);
  gemm_bt<ACT_U><<<1024, 256, 0, stream>>>(zbuf, Wb + 4 * 1048576, ubuf, vbuf, nullptr);
  // r = sigmoid -> kbuf (reuse)
  zgen<<<16384, 256, 0, stream>>>(x, mx_r, zbuf);
  gemm_bt<ACT_SIG><<<1024, 256, 0, stream>>>(zbuf, Wb + 0, kbuf, nullptr, nullptr);
  // g = sigmoid -> vbuf (reuse)
  zgen<<<16384, 256, 0, stream>>>(x, mx_g, zbuf);
  gemm_bt<ACT_SIG><<<1024, 256, 0, stream>>>(zbuf, Wb + 5 * 1048576, vbuf, nullptr, nullptr);

  // recurrence (chunked parallel scan); mixed overwrites dec in scan3
  scan1<<<1024, 256, 0, stream>>>(dec, ubuf, Ac, Sc);
  scan2<<<16, 256, 0, stream>>>(Ac, Sc, Inb);
  scan3<<<1024, 256, 0, stream>>>(dec, ubuf, kbuf, Inb);

  // groupnorm(mixed) * g -> h (bf16, into zbuf)
  gnorm<<<65536, 256, 0, stream>>>(dec, vbuf, gn_w, gn_b, zbuf);

  // out = h @ W_out^T + b_out, f32
  gemm_bt<ACT_BIAS><<<1024, 256, 0, stream>>>(zbuf, Wb + 6 * 1048576, (float*)d_out, nullptr, b_out);
}

// Round 5
// 588.436 us; speedup vs baseline: 1.1751x; 1.1357x over previous
//
#include <hip/hip_runtime.h>
#include <cstdint>
#include <cstddef>

#define D_MODEL 1024
#define SEQ_LEN 4096
#define NBATCH  4
#define M_ROWS  (NBATCH * SEQ_LEN)   // 16384 rows (b*4096+n)
#define NCHUNK  64
#define CHLEN   64                   // SEQ_LEN / NCHUNK
#define GN_EPS_F 0.00064f

typedef unsigned short u16;
typedef __attribute__((ext_vector_type(4))) float f32x4;
typedef __attribute__((ext_vector_type(8))) __bf16 bf16x8;

enum { ACT_DECAY = 0, ACT_TANH, ACT_VMUL, ACT_U, ACT_SIG, ACT_BIAS };

__device__ __forceinline__ u16 f2bf(float f) {
  union { float f; uint32_t u; } un; un.f = f;
  uint32_t r = (un.u + 0x7FFFu + ((un.u >> 16) & 1u)) >> 16;  // RNE
  return (u16)r;
}
__device__ __forceinline__ float bf2f(u16 h) {
  union { uint32_t u; float f; } un; un.u = ((uint32_t)h) << 16;
  return un.f;
}
__device__ __forceinline__ float sigm(float y) { return 1.f / (1.f + expf(-y)); }

// async global->LDS, 16B/lane. LDS dst = wave-uniform base (HW adds lane*16).
__device__ __forceinline__ void load_lds16(const u16* g, u16* l) {
  __builtin_amdgcn_global_load_lds(
      (const __attribute__((address_space(1))) void*)g,
      (__attribute__((address_space(3))) void*)l, 16, 0, 0);
}

// ---------------- weights f32 -> bf16 (7 matrices, contiguous slots) ----------
__global__ __launch_bounds__(256) void wconv(
    const float* __restrict__ w0, const float* __restrict__ w1,
    const float* __restrict__ w2, const float* __restrict__ w3,
    const float* __restrict__ w4, const float* __restrict__ w5,
    const float* __restrict__ w6, u16* __restrict__ Wb) {
  const int gid = blockIdx.x * 256 + threadIdx.x;  // over 7*262144 float4s
  const int m = gid >> 18;
  const int off = gid & 262143;
  const float* src;
  switch (m) {
    case 0: src = w0; break; case 1: src = w1; break; case 2: src = w2; break;
    case 3: src = w3; break; case 4: src = w4; break; case 5: src = w5; break;
    default: src = w6; break;
  }
  const float4 v = ((const float4*)src)[off];
  ushort4 o;
  o.x = f2bf(v.x); o.y = f2bf(v.y); o.z = f2bf(v.z); o.w = f2bf(v.w);
  ((ushort4*)Wb)[gid] = o;
}

// ---------------- z = x + (prev - x) * mix  -> bf16 ---------------------------
__global__ __launch_bounds__(256) void zgen(
    const float* __restrict__ x, const float* __restrict__ mix,
    u16* __restrict__ z) {
  const int gid = blockIdx.x * 256 + threadIdx.x;  // over M_ROWS*D/4 = 4,194,304
  const int dv = gid & 255;                        // float4 index within row
  const int n = (gid >> 8) & (SEQ_LEN - 1);
  const float4 xv = ((const float4*)x)[gid];
  float4 pv = make_float4(0.f, 0.f, 0.f, 0.f);
  if (n > 0) pv = ((const float4*)x)[gid - 256];   // previous token, same batch
  const float4 mv = ((const float4*)mix)[dv];
  ushort4 o;
  o.x = f2bf(xv.x + (pv.x - xv.x) * mv.x);
  o.y = f2bf(xv.y + (pv.y - xv.y) * mv.y);
  o.z = f2bf(xv.z + (pv.z - xv.z) * mv.z);
  o.w = f2bf(xv.w + (pv.w - xv.w) * mv.w);
  ((ushort4*)z)[gid] = o;
}

// ---------------- bf16 GEMM: out = A @ W^T, fused activation epilogue --------
// 128x128 tile, BK=32, 4 waves (2x2), global_load_lds width 16.
// Double-buffered 2-phase pipeline with COUNTED vmcnt (T4): next tile's 4
// loads stay in flight across the barrier (vmcnt(4)); raw s_barrier (no
// drain). Chunked XCD swizzle keeps each A-panel in one XCD's L2.
template <int ACT>
__global__ __launch_bounds__(256, 4) void gemm_bt(
    const u16* __restrict__ A,   // [M][1024] bf16
    const u16* __restrict__ Bw,  // [1024][1024] bf16 row-major (torch W)
    void* __restrict__ outp,
    const u16* __restrict__ aux,     // kv for ACT_U, k for ACT_VMUL
    const float* __restrict__ bias) {  // for ACT_BIAS
  __shared__ __align__(16) u16 Al[2][128 * 32];
  __shared__ __align__(16) u16 Bl[2][128 * 32];
  const int tid = threadIdx.x;
  const int lane = tid & 63;
  const int wid = tid >> 6;

  // chunked XCD swizzle: bid%8 = XCD; each XCD owns 16 m-panels x 8 n-tiles.
  const int bid = blockIdx.x;                  // 0..1023
  const int swz = (bid & 7) * 128 + (bid >> 3);
  const int m0 = (swz >> 3) * 128;
  const int n0 = (swz & 7) * 128;

  const int wm = (wid >> 1) * 64;
  const int wn = (wid & 1) * 64;
  const int lr = lane & 15;
  const int lk = lane >> 4;

  // staging: wave w stages rows w*16..w*16+15 (and +64); lane i: row w*16+i/4,
  // col (i%4)*8; LDS linear chunk byte i*16 matches row-major exactly.
  const int srow = tid >> 2;
  const int scol = (tid & 3) * 8;
  const u16* ga0 = A + (size_t)(m0 + srow) * D_MODEL + scol;
  const u16* ga1 = ga0 + (size_t)64 * D_MODEL;
  const u16* gb0 = Bw + (size_t)(n0 + srow) * D_MODEL + scol;
  const u16* gb1 = gb0 + (size_t)64 * D_MODEL;

  f32x4 acc[4][4];
  const f32x4 z4 = {0.f, 0.f, 0.f, 0.f};
#pragma unroll
  for (int i = 0; i < 4; i++)
#pragma unroll
    for (int j = 0; j < 4; j++) acc[i][j] = z4;

  // prologue: stage tile 0 into buffer 0 (loads left in flight)
  load_lds16(ga0, &Al[0][wid * 512]);
  load_lds16(ga1, &Al[0][2048 + wid * 512]);
  load_lds16(gb0, &Bl[0][wid * 512]);
  load_lds16(gb1, &Bl[0][2048 + wid * 512]);

  int cur = 0;
  for (int kt = 0; kt < D_MODEL; kt += 32) {
    if (kt + 32 < D_MODEL) {
      const int nb = cur ^ 1;
      load_lds16(ga0 + kt + 32, &Al[nb][wid * 512]);
      load_lds16(ga1 + kt + 32, &Al[nb][2048 + wid * 512]);
      load_lds16(gb0 + kt + 32, &Bl[nb][wid * 512]);
      load_lds16(gb1 + kt + 32, &Bl[nb][2048 + wid * 512]);
      asm volatile("s_waitcnt vmcnt(4)" ::: "memory");  // tile t landed; t+1 in flight
    } else {
      asm volatile("s_waitcnt vmcnt(0)" ::: "memory");  // last tile: drain
    }
    __builtin_amdgcn_s_barrier();        // all waves' tile-t LDS writes visible
    __builtin_amdgcn_sched_barrier(0);   // pin: no ds_read hoists above this
    bf16x8 af[4], bfr[4];
#pragma unroll
    for (int i = 0; i < 4; i++) {
      af[i]  = *reinterpret_cast<const bf16x8*>(&Al[cur][(wm + i * 16 + lr) * 32 + lk * 8]);
      bfr[i] = *reinterpret_cast<const bf16x8*>(&Bl[cur][(wn + i * 16 + lr) * 32 + lk * 8]);
    }
#pragma unroll
    for (int i = 0; i < 4; i++)
#pragma unroll
      for (int j = 0; j < 4; j++)
        acc[i][j] = __builtin_amdgcn_mfma_f32_16x16x32_bf16(af[i], bfr[j], acc[i][j], 0, 0, 0);
    __builtin_amdgcn_s_barrier();        // readers of buf[cur] done (lgkmcnt
    cur ^= 1;                            // enforced by MFMA deps) before t+1 stages it
  }

  // epilogue; C/D layout: col = lane&15, row = (lane>>4)*4 + e  [m89-verified]
#pragma unroll
  for (int i = 0; i < 4; i++) {
#pragma unroll
    for (int j = 0; j < 4; j++) {
#pragma unroll
      for (int e = 0; e < 4; e++) {
        const int row = m0 + wm + i * 16 + lk * 4 + e;
        const int col = n0 + wn + j * 16 + lr;
        const size_t idx = (size_t)row * D_MODEL + col;
        const float y = acc[i][j][e];
        if constexpr (ACT == ACT_DECAY) {
          ((float*)outp)[idx] = 1.f / (1.f + expf(y));  // exp(-softplus(y)) = sigmoid(-y)
        } else if constexpr (ACT == ACT_TANH) {
          ((u16*)outp)[idx] = f2bf(tanhf(y));
        } else if constexpr (ACT == ACT_VMUL) {
          ((u16*)outp)[idx] = f2bf(y * bf2f(aux[idx]));          // kv = v * k
        } else if constexpr (ACT == ACT_U) {
          ((u16*)outp)[idx] = f2bf(sigm(y) * bf2f(aux[idx]));    // u = alpha * kv
        } else if constexpr (ACT == ACT_SIG) {
          ((u16*)outp)[idx] = f2bf(sigm(y));
        } else {  // ACT_BIAS
          ((float*)outp)[idx] = y + bias[col];
        }
      }
    }
  }
}

// ---------------- chunked scan: state = state*decay + u; mixed = r*state -----
__global__ __launch_bounds__(256) void scan1(
    const float* __restrict__ dec, const u16* __restrict__ u,
    float* __restrict__ Ac, float* __restrict__ Sc) {
  const int gid = blockIdx.x * 256 + threadIdx.x;  // c*4096 + b*1024 + d
  const int d = gid & 1023;
  const int b = (gid >> 10) & 3;
  const int c = gid >> 12;
  const size_t base = ((size_t)b * SEQ_LEN + (size_t)c * CHLEN) * D_MODEL + d;
  float A = 1.f, S = 0.f;
#pragma unroll 4
  for (int t = 0; t < CHLEN; t++) {
    const size_t off = base + (size_t)t * D_MODEL;
    const float dd = dec[off];
    S = S * dd + bf2f(u[off]);
    A *= dd;
  }
  Ac[gid] = A;
  Sc[gid] = S;
}

__global__ __launch_bounds__(256) void scan2(
    const float* __restrict__ Ac, const float* __restrict__ Sc,
    float* __restrict__ In) {
  const int gid = blockIdx.x * 256 + threadIdx.x;  // b*1024 + d, 4096 total
  float carry = 0.f;
#pragma unroll 4
  for (int c = 0; c < NCHUNK; c++) {
    const int i = c * 4096 + gid;
    In[i] = carry;
    carry = carry * Ac[i] + Sc[i];
  }
}

__global__ __launch_bounds__(256) void scan3(
    float* __restrict__ decmix, const u16* __restrict__ u,
    const u16* __restrict__ r, const float* __restrict__ In) {
  const int gid = blockIdx.x * 256 + threadIdx.x;
  const int d = gid & 1023;
  const int b = (gid >> 10) & 3;
  const int c = gid >> 12;
  const size_t base = ((size_t)b * SEQ_LEN + (size_t)c * CHLEN) * D_MODEL + d;
  float state = In[gid];
#pragma unroll 4
  for (int t = 0; t < CHLEN; t++) {
    const size_t off = base + (size_t)t * D_MODEL;
    state = state * decmix[off] + bf2f(u[off]);
    decmix[off] = bf2f(r[off]) * state;  // read-before-write within thread: safe
  }
}

// ---------------- GroupNorm(H=16, 64ch) * g -> bf16 ---------------------------
__global__ __launch_bounds__(256) void gnorm(
    const float* __restrict__ mixed, const u16* __restrict__ g,
    const float* __restrict__ gw, const float* __restrict__ gb,
    u16* __restrict__ h) {
  const int wid = threadIdx.x >> 6;
  const int lane = threadIdx.x & 63;
  const int grp = blockIdx.x * 4 + wid;  // over M_ROWS*16 = 262144
  const int row = grp >> 4;
  const int hh = grp & 15;
  const int d = hh * 64 + lane;
  const size_t idx = (size_t)row * D_MODEL + d;
  const float v = mixed[idx];
  float s = v, s2 = v * v;
#pragma unroll
  for (int m = 32; m > 0; m >>= 1) {
    s += __shfl_xor(s, m, 64);
    s2 += __shfl_xor(s2, m, 64);
  }
  const float mu = s * (1.f / 64.f);
  float var = s2 * (1.f / 64.f) - mu * mu;
  const float inv = 1.f / sqrtf(var + GN_EPS_F);
  const float mn = (v - mu) * inv * gw[d] + gb[d];
  h[idx] = f2bf(mn * bf2f(g[idx]));
}

// ---------------- host ---------------------------------------------------------
extern "C" void kernel_launch(void* const* d_in, const int* in_sizes, int n_in,
                              void* d_out, int out_size, void* d_ws, size_t ws_size,
                              hipStream_t stream) {
  (void)in_sizes; (void)n_in; (void)out_size; (void)ws_size;
  const float* x    = (const float*)d_in[0];
  const float* mx_r = (const float*)d_in[1];
  const float* mx_w = (const float*)d_in[2];
  const float* mx_k = (const float*)d_in[3];
  const float* mx_v = (const float*)d_in[4];
  const float* mx_a = (const float*)d_in[5];
  const float* mx_g = (const float*)d_in[6];
  const float* W_r  = (const float*)d_in[7];
  const float* W_w  = (const float*)d_in[8];
  const float* W_k  = (const float*)d_in[9];
  const float* W_v  = (const float*)d_in[10];
  const float* W_a  = (const float*)d_in[11];
  const float* W_g  = (const float*)d_in[12];
  const float* W_o  = (const float*)d_in[13];
  const float* b_out = (const float*)d_in[14];
  const float* gn_w  = (const float*)d_in[15];
  const float* gn_b  = (const float*)d_in[16];

  // Workspace plan (209 MB total; buffers reused across phases):
  //   0   : Wb    14MB | 14: Ac 1MB | 15: Sc 1MB | 16: zbuf 32MB (z; later h)
  //   48  : dec   64MB (decay f32; scan3 overwrites with mixed f32)
  //   112 : ubuf  32MB (u bf16) | 144: kbuf 32MB (k; later r)
  //   176 : vbuf  32MB (kv; later g) | 208: In 1MB
  char* ws = (char*)d_ws;
  const size_t MB = 1024ull * 1024ull;
  u16*   Wb   = (u16*)(ws);
  float* Ac   = (float*)(ws + 14 * MB);
  float* Sc   = (float*)(ws + 15 * MB);
  u16*   zbuf = (u16*)(ws + 16 * MB);
  float* dec  = (float*)(ws + 48 * MB);
  u16*   ubuf = (u16*)(ws + 112 * MB);
  u16*   kbuf = (u16*)(ws + 144 * MB);
  u16*   vbuf = (u16*)(ws + 176 * MB);
  float* Inb  = (float*)(ws + 208 * MB);

  wconv<<<7168, 256, 0, stream>>>(W_r, W_w, W_k, W_v, W_a, W_g, W_o, Wb);

  // decay = sigmoid(-lin_w), f32
  zgen<<<16384, 256, 0, stream>>>(x, mx_w, zbuf);
  gemm_bt<ACT_DECAY><<<1024, 256, 0, stream>>>(zbuf, Wb + 1 * 1048576, dec, nullptr, nullptr);
  // k = tanh -> kbuf
  zgen<<<16384, 256, 0, stream>>>(x, mx_k, zbuf);
  gemm_bt<ACT_TANH><<<1024, 256, 0, stream>>>(zbuf, Wb + 2 * 1048576, kbuf, nullptr, nullptr);
  // kv = v * k -> vbuf
  zgen<<<16384, 256, 0, stream>>>(x, mx_v, zbuf);
  gemm_bt<ACT_VMUL><<<1024, 256, 0, stream>>>(zbuf, Wb + 3 * 1048576, vbuf, kbuf, nullptr);
  // u = sigmoid(lin_a) * kv -> ubuf (bf16)
  zgen<<<16384, 256, 0, stream>>>(x, mx_a, zbuf);
  gemm_bt<ACT_U><<<1024, 256, 0, stream>>>(zbuf, Wb + 4 * 1048576, ubuf, vbuf, nullptr);
  // r = sigmoid -> kbuf (reuse)
  zgen<<<16384, 256, 0, stream>>>(x, mx_r, zbuf);
  gemm_bt<ACT_SIG><<<1024, 256, 0, stream>>>(zbuf, Wb + 0, kbuf, nullptr, nullptr);
  // g = sigmoid -> vbuf (reuse)
  zgen<<<16384, 256, 0, stream>>>(x, mx_g, zbuf);
  gemm_bt<ACT_SIG><<<1024, 256, 0, stream>>>(zbuf, Wb + 5 * 1048576, vbuf, nullptr, nullptr);

  // recurrence (chunked parallel scan); mixed overwrites dec in scan3
  scan1<<<1024, 256, 0, stream>>>(dec, ubuf, Ac, Sc);
  scan2<<<16, 256, 0, stream>>>(Ac, Sc, Inb);
  scan3<<<1024, 256, 0, stream>>>(dec, ubuf, kbuf, Inb);

  // groupnorm(mixed) * g -> h (bf16, into zbuf)
  gnorm<<<65536, 256, 0, stream>>>(dec, vbuf, gn_w, gn_b, zbuf);

  // out = h @ W_out^T + b_out, f32
  gemm_bt<ACT_BIAS><<<1024, 256, 0, stream>>>(zbuf, Wb + 6 * 1048576, (float*)d_out, nullptr, b_out);
}

// Round 6
// 566.478 us; speedup vs baseline: 1.2206x; 1.0388x over previous
//
#include <hip/hip_runtime.h>
#include <cstdint>
#include <cstddef>

#define D_MODEL 1024
#define SEQ_LEN 4096
#define NBATCH  4
#define M_ROWS  (NBATCH * SEQ_LEN)   // 16384 rows (b*4096+n)
#define NCHUNK  64
#define CHLEN   64                   // SEQ_LEN / NCHUNK
#define GN_EPS_F 0.00064f

typedef unsigned short u16;
typedef __attribute__((ext_vector_type(4))) float f32x4;
typedef __attribute__((ext_vector_type(8))) __bf16 bf16x8;

enum { ACT_DECAY = 0, ACT_TANH, ACT_VMUL, ACT_U, ACT_SIG, ACT_BIAS };

__device__ __forceinline__ u16 f2bf(float f) {
  union { float f; uint32_t u; } un; un.f = f;
  uint32_t r = (un.u + 0x7FFFu + ((un.u >> 16) & 1u)) >> 16;  // RNE
  return (u16)r;
}
__device__ __forceinline__ float bf2f(u16 h) {
  union { uint32_t u; float f; } un; un.u = ((uint32_t)h) << 16;
  return un.f;
}
__device__ __forceinline__ float sigm(float y) { return 1.f / (1.f + expf(-y)); }

// async global->LDS, 16B/lane. LDS dst = wave-uniform base (HW adds lane*16).
__device__ __forceinline__ void load_lds16(const u16* g, u16* l) {
  __builtin_amdgcn_global_load_lds(
      (const __attribute__((address_space(1))) void*)g,
      (__attribute__((address_space(3))) void*)l, 16, 0, 0);
}

// ---------------- weights f32 -> bf16 (7 matrices, contiguous slots) ----------
__global__ __launch_bounds__(256) void wconv(
    const float* __restrict__ w0, const float* __restrict__ w1,
    const float* __restrict__ w2, const float* __restrict__ w3,
    const float* __restrict__ w4, const float* __restrict__ w5,
    const float* __restrict__ w6, u16* __restrict__ Wb) {
  const int gid = blockIdx.x * 256 + threadIdx.x;  // over 7*262144 float4s
  const int m = gid >> 18;
  const int off = gid & 262143;
  const float* src;
  switch (m) {
    case 0: src = w0; break; case 1: src = w1; break; case 2: src = w2; break;
    case 3: src = w3; break; case 4: src = w4; break; case 5: src = w5; break;
    default: src = w6; break;
  }
  const float4 v = ((const float4*)src)[off];
  ushort4 o;
  o.x = f2bf(v.x); o.y = f2bf(v.y); o.z = f2bf(v.z); o.w = f2bf(v.w);
  ((ushort4*)Wb)[gid] = o;
}

// ---------------- z = x + (prev - x) * mix  -> bf16 ---------------------------
__global__ __launch_bounds__(256) void zgen(
    const float* __restrict__ x, const float* __restrict__ mix,
    u16* __restrict__ z) {
  const int gid = blockIdx.x * 256 + threadIdx.x;  // over M_ROWS*D/4 = 4,194,304
  const int dv = gid & 255;                        // float4 index within row
  const int n = (gid >> 8) & (SEQ_LEN - 1);
  const float4 xv = ((const float4*)x)[gid];
  float4 pv = make_float4(0.f, 0.f, 0.f, 0.f);
  if (n > 0) pv = ((const float4*)x)[gid - 256];   // previous token, same batch
  const float4 mv = ((const float4*)mix)[dv];
  ushort4 o;
  o.x = f2bf(xv.x + (pv.x - xv.x) * mv.x);
  o.y = f2bf(xv.y + (pv.y - xv.y) * mv.y);
  o.z = f2bf(xv.z + (pv.z - xv.z) * mv.z);
  o.w = f2bf(xv.w + (pv.w - xv.w) * mv.w);
  ((ushort4*)z)[gid] = o;
}

// ---------------- bf16 GEMM: out = A @ W^T, 256x256 8-phase schedule ---------
// 256x256 tile, BK=64, 8 waves (2Mx4N), 512 thr, LDS 128KB (2 dbuf).
// Per K-tile: 4 phases (C-quadrants), 16 MFMA each; counted vmcnt (4/6) only;
// raw s_barrier + sched_barrier(0); setprio around MFMA (T5 pays on 8-phase).
// LDS bank-conflict fix per rule #21: linear LDS dest + inverse-swizzled
// GLOBAL source (chunk ^= row&7 per 16B chunk) + swizzled ds_read address.
template <int ACT>
__global__ __launch_bounds__(512, 2) void gemm_bt(
    const u16* __restrict__ A,   // [M][1024] bf16
    const u16* __restrict__ Bw,  // [1024][1024] bf16 row-major (torch W)
    void* __restrict__ outp,
    const u16* __restrict__ aux,     // kv for ACT_U, k for ACT_VMUL
    const float* __restrict__ bias) {  // for ACT_BIAS
  __shared__ __align__(16) u16 AL[2][256 * 64];   // 64 KB
  __shared__ __align__(16) u16 BL[2][256 * 64];   // 64 KB
  const int tid = threadIdx.x;
  const int lane = tid & 63;
  const int wid = tid >> 6;          // 0..7
  const int wr = wid >> 2;           // 0..1  (M half)
  const int wc = wid & 3;            // 0..3  (N quarter)
  const int lr = lane & 15;
  const int lk = lane >> 4;

  // XCD-chunked swizzle: 256 blocks, 8 XCDs, 32 contiguous logical tiles each
  const int bid = blockIdx.x;
  const int logical = (bid & 7) * 32 + (bid >> 3);
  const int m0 = (logical >> 2) * 256;
  const int n0 = (logical & 3) * 256;

  // staging geometry: gload g covers tile rows g*64..+64 (A) / B-rows same.
  // thread t: row-in-chunk = t>>3, 16B-chunk = t&7, source chunk XOR (row&7).
  const int srow = tid >> 3;
  const int ssw  = ((tid & 7) ^ (srow & 7)) * 8;   // u16 col offset, pre-swizzled
  const u16* gA = A  + (size_t)(m0 + srow) * D_MODEL + ssw;
  const u16* gB = Bw + (size_t)(n0 + srow) * D_MODEL + ssw;
  // LDS dest (wave-uniform): g*4096 + wid*512 u16
#define SA(g, bufi, kt) load_lds16(gA + (size_t)(g)*64*D_MODEL + (kt), &AL[bufi][(g)*4096 + wid*512])
#define SB(g, bufi, kt) load_lds16(gB + (size_t)(g)*64*D_MODEL + (kt), &BL[bufi][(g)*4096 + wid*512])

  // ds_read bases: row R -> u16 R*64 + swizzled chunk ((kk*4+lk)^(R&7))*8
  const int rbA = (wr * 128 + lr) * 64;
  const int rbB = (wc * 64 + lr) * 64;
  const int sw0 = ((lk)     ^ (lr & 7)) << 3;
  const int sw1 = ((lk + 4) ^ (lr & 7)) << 3;

  f32x4 acc[8][4];
  const f32x4 z4 = {0.f, 0.f, 0.f, 0.f};
#pragma unroll
  for (int i = 0; i < 8; i++)
#pragma unroll
    for (int j = 0; j < 4; j++) acc[i][j] = z4;

  // prologue: tile 0 into buf 0, issue order = consumption order
  SB(0, 0, 0); SB(1, 0, 0); SB(2, 0, 0); SB(3, 0, 0);
  SA(0, 0, 0); SA(2, 0, 0); SA(1, 0, 0); SA(3, 0, 0);

  int cur = 0;
  for (int t = 0; t < 16; ++t) {
    const int nxt = cur ^ 1;
    const int ktn = (t + 1) * 64;
    const bool more = (t < 15);
    const u16* uA = AL[cur];
    const u16* uB = BL[cur];
    bf16x8 a0[4][2], a1[4][2], b[4][2];

    // ---- P1: quadrant (mh=0, nj=0..1)
    if (more) { SB(0, nxt, ktn); SB(1, nxt, ktn); }
    if (more) asm volatile("s_waitcnt vmcnt(4)" ::: "memory");  // tile t: B0-3,A0,A2 landed
    else      asm volatile("s_waitcnt vmcnt(2)" ::: "memory");
    __builtin_amdgcn_s_barrier();
    __builtin_amdgcn_sched_barrier(0);
#pragma unroll
    for (int mi = 0; mi < 4; ++mi) {
      a0[mi][0] = *(const bf16x8*)&uA[rbA + mi * 1024 + sw0];
      a0[mi][1] = *(const bf16x8*)&uA[rbA + mi * 1024 + sw1];
    }
#pragma unroll
    for (int nj = 0; nj < 2; ++nj) {
      b[nj][0] = *(const bf16x8*)&uB[rbB + nj * 1024 + sw0];
      b[nj][1] = *(const bf16x8*)&uB[rbB + nj * 1024 + sw1];
    }
    __builtin_amdgcn_s_setprio(1);
#pragma unroll
    for (int mi = 0; mi < 4; ++mi)
#pragma unroll
      for (int nj = 0; nj < 2; ++nj)
#pragma unroll
        for (int kk = 0; kk < 2; ++kk)
          acc[mi][nj] = __builtin_amdgcn_mfma_f32_16x16x32_bf16(a0[mi][kk], b[nj][kk], acc[mi][nj], 0, 0, 0);
    __builtin_amdgcn_s_setprio(0);

    // ---- P2: quadrant (mh=0, nj=2..3)
#pragma unroll
    for (int nj = 2; nj < 4; ++nj) {
      b[nj][0] = *(const bf16x8*)&uB[rbB + nj * 1024 + sw0];
      b[nj][1] = *(const bf16x8*)&uB[rbB + nj * 1024 + sw1];
    }
    if (more) { SB(2, nxt, ktn); SB(3, nxt, ktn); }
    __builtin_amdgcn_s_barrier();
    __builtin_amdgcn_sched_barrier(0);
    __builtin_amdgcn_s_setprio(1);
#pragma unroll
    for (int mi = 0; mi < 4; ++mi)
#pragma unroll
      for (int nj = 2; nj < 4; ++nj)
#pragma unroll
        for (int kk = 0; kk < 2; ++kk)
          acc[mi][nj] = __builtin_amdgcn_mfma_f32_16x16x32_bf16(a0[mi][kk], b[nj][kk], acc[mi][nj], 0, 0, 0);
    __builtin_amdgcn_s_setprio(0);

    // ---- P3: quadrant (mh=1, nj=0..1)
#pragma unroll
    for (int mi = 0; mi < 4; ++mi) {
      a1[mi][0] = *(const bf16x8*)&uA[rbA + 4096 + mi * 1024 + sw0];
      a1[mi][1] = *(const bf16x8*)&uA[rbA + 4096 + mi * 1024 + sw1];
    }
    if (more) { SA(0, nxt, ktn); SA(2, nxt, ktn); }
    if (more) asm volatile("s_waitcnt vmcnt(6)" ::: "memory");  // tile t: A1,A3 landed
    else      asm volatile("s_waitcnt vmcnt(0)" ::: "memory");
    __builtin_amdgcn_s_barrier();
    __builtin_amdgcn_sched_barrier(0);
    __builtin_amdgcn_s_setprio(1);
#pragma unroll
    for (int mi = 0; mi < 4; ++mi)
#pragma unroll
      for (int nj = 0; nj < 2; ++nj)
#pragma unroll
        for (int kk = 0; kk < 2; ++kk)
          acc[4 + mi][nj] = __builtin_amdgcn_mfma_f32_16x16x32_bf16(a1[mi][kk], b[nj][kk], acc[4 + mi][nj], 0, 0, 0);
    __builtin_amdgcn_s_setprio(0);

    // ---- P4: quadrant (mh=1, nj=2..3)
    if (more) { SA(1, nxt, ktn); SA(3, nxt, ktn); }
    __builtin_amdgcn_s_barrier();
    __builtin_amdgcn_sched_barrier(0);
    __builtin_amdgcn_s_setprio(1);
#pragma unroll
    for (int mi = 0; mi < 4; ++mi)
#pragma unroll
      for (int nj = 2; nj < 4; ++nj)
#pragma unroll
        for (int kk = 0; kk < 2; ++kk)
          acc[4 + mi][nj] = __builtin_amdgcn_mfma_f32_16x16x32_bf16(a1[mi][kk], b[nj][kk], acc[4 + mi][nj], 0, 0, 0);
    __builtin_amdgcn_s_setprio(0);
    cur = nxt;
  }
#undef SA
#undef SB

  // epilogue; C/D layout: col = lane&15, row = (lane>>4)*4 + e  [m89-verified]
#pragma unroll
  for (int mh = 0; mh < 2; ++mh) {
#pragma unroll
    for (int mi = 0; mi < 4; ++mi) {
#pragma unroll
      for (int nj = 0; nj < 4; ++nj) {
#pragma unroll
        for (int e = 0; e < 4; ++e) {
          const int row = m0 + wr * 128 + mh * 64 + mi * 16 + lk * 4 + e;
          const int col = n0 + wc * 64 + nj * 16 + lr;
          const size_t idx = (size_t)row * D_MODEL + col;
          const float y = acc[mh * 4 + mi][nj][e];
          if constexpr (ACT == ACT_DECAY) {
            ((float*)outp)[idx] = 1.f / (1.f + expf(y));  // exp(-softplus) = sigmoid(-y)
          } else if constexpr (ACT == ACT_TANH) {
            ((u16*)outp)[idx] = f2bf(tanhf(y));
          } else if constexpr (ACT == ACT_VMUL) {
            ((u16*)outp)[idx] = f2bf(y * bf2f(aux[idx]));          // kv = v * k
          } else if constexpr (ACT == ACT_U) {
            ((u16*)outp)[idx] = f2bf(sigm(y) * bf2f(aux[idx]));    // u = alpha * kv
          } else if constexpr (ACT == ACT_SIG) {
            ((u16*)outp)[idx] = f2bf(sigm(y));
          } else {  // ACT_BIAS
            ((float*)outp)[idx] = y + bias[col];
          }
        }
      }
    }
  }
}

// ---------------- chunked scan: state = state*decay + u; mixed = r*state -----
__global__ __launch_bounds__(256) void scan1(
    const float* __restrict__ dec, const u16* __restrict__ u,
    float* __restrict__ Ac, float* __restrict__ Sc) {
  const int gid = blockIdx.x * 256 + threadIdx.x;  // c*4096 + b*1024 + d
  const int d = gid & 1023;
  const int b = (gid >> 10) & 3;
  const int c = gid >> 12;
  const size_t base = ((size_t)b * SEQ_LEN + (size_t)c * CHLEN) * D_MODEL + d;
  float A = 1.f, S = 0.f;
#pragma unroll 4
  for (int t = 0; t < CHLEN; t++) {
    const size_t off = base + (size_t)t * D_MODEL;
    const float dd = dec[off];
    S = S * dd + bf2f(u[off]);
    A *= dd;
  }
  Ac[gid] = A;
  Sc[gid] = S;
}

__global__ __launch_bounds__(256) void scan2(
    const float* __restrict__ Ac, const float* __restrict__ Sc,
    float* __restrict__ In) {
  const int gid = blockIdx.x * 256 + threadIdx.x;  // b*1024 + d, 4096 total
  float carry = 0.f;
#pragma unroll 4
  for (int c = 0; c < NCHUNK; c++) {
    const int i = c * 4096 + gid;
    In[i] = carry;
    carry = carry * Ac[i] + Sc[i];
  }
}

__global__ __launch_bounds__(256) void scan3(
    float* __restrict__ decmix, const u16* __restrict__ u,
    const u16* __restrict__ r, const float* __restrict__ In) {
  const int gid = blockIdx.x * 256 + threadIdx.x;
  const int d = gid & 1023;
  const int b = (gid >> 10) & 3;
  const int c = gid >> 12;
  const size_t base = ((size_t)b * SEQ_LEN + (size_t)c * CHLEN) * D_MODEL + d;
  float state = In[gid];
#pragma unroll 4
  for (int t = 0; t < CHLEN; t++) {
    const size_t off = base + (size_t)t * D_MODEL;
    state = state * decmix[off] + bf2f(u[off]);
    decmix[off] = bf2f(r[off]) * state;  // read-before-write within thread: safe
  }
}

// ---------------- GroupNorm(H=16, 64ch) * g -> bf16 ---------------------------
__global__ __launch_bounds__(256) void gnorm(
    const float* __restrict__ mixed, const u16* __restrict__ g,
    const float* __restrict__ gw, const float* __restrict__ gb,
    u16* __restrict__ h) {
  const int wid = threadIdx.x >> 6;
  const int lane = threadIdx.x & 63;
  const int grp = blockIdx.x * 4 + wid;  // over M_ROWS*16 = 262144
  const int row = grp >> 4;
  const int hh = grp & 15;
  const int d = hh * 64 + lane;
  const size_t idx = (size_t)row * D_MODEL + d;
  const float v = mixed[idx];
  float s = v, s2 = v * v;
#pragma unroll
  for (int m = 32; m > 0; m >>= 1) {
    s += __shfl_xor(s, m, 64);
    s2 += __shfl_xor(s2, m, 64);
  }
  const float mu = s * (1.f / 64.f);
  float var = s2 * (1.f / 64.f) - mu * mu;
  const float inv = 1.f / sqrtf(var + GN_EPS_F);
  const float mn = (v - mu) * inv * gw[d] + gb[d];
  h[idx] = f2bf(mn * bf2f(g[idx]));
}

// ---------------- host ---------------------------------------------------------
extern "C" void kernel_launch(void* const* d_in, const int* in_sizes, int n_in,
                              void* d_out, int out_size, void* d_ws, size_t ws_size,
                              hipStream_t stream) {
  (void)in_sizes; (void)n_in; (void)out_size; (void)ws_size;
  const float* x    = (const float*)d_in[0];
  const float* mx_r = (const float*)d_in[1];
  const float* mx_w = (const float*)d_in[2];
  const float* mx_k = (const float*)d_in[3];
  const float* mx_v = (const float*)d_in[4];
  const float* mx_a = (const float*)d_in[5];
  const float* mx_g = (const float*)d_in[6];
  const float* W_r  = (const float*)d_in[7];
  const float* W_w  = (const float*)d_in[8];
  const float* W_k  = (const float*)d_in[9];
  const float* W_v  = (const float*)d_in[10];
  const float* W_a  = (const float*)d_in[11];
  const float* W_g  = (const float*)d_in[12];
  const float* W_o  = (const float*)d_in[13];
  const float* b_out = (const float*)d_in[14];
  const float* gn_w  = (const float*)d_in[15];
  const float* gn_b  = (const float*)d_in[16];

  // Workspace plan (209 MB total; buffers reused across phases):
  //   0   : Wb    14MB | 14: Ac 1MB | 15: Sc 1MB | 16: zbuf 32MB (z; later h)
  //   48  : dec   64MB (decay f32; scan3 overwrites with mixed f32)
  //   112 : ubuf  32MB (u bf16) | 144: kbuf 32MB (k; later r)
  //   176 : vbuf  32MB (kv; later g) | 208: In 1MB
  char* ws = (char*)d_ws;
  const size_t MB = 1024ull * 1024ull;
  u16*   Wb   = (u16*)(ws);
  float* Ac   = (float*)(ws + 14 * MB);
  float* Sc   = (float*)(ws + 15 * MB);
  u16*   zbuf = (u16*)(ws + 16 * MB);
  float* dec  = (float*)(ws + 48 * MB);
  u16*   ubuf = (u16*)(ws + 112 * MB);
  u16*   kbuf = (u16*)(ws + 144 * MB);
  u16*   vbuf = (u16*)(ws + 176 * MB);
  float* Inb  = (float*)(ws + 208 * MB);

  wconv<<<7168, 256, 0, stream>>>(W_r, W_w, W_k, W_v, W_a, W_g, W_o, Wb);

  // decay = sigmoid(-lin_w), f32
  zgen<<<16384, 256, 0, stream>>>(x, mx_w, zbuf);
  gemm_bt<ACT_DECAY><<<256, 512, 0, stream>>>(zbuf, Wb + 1 * 1048576, dec, nullptr, nullptr);
  // k = tanh -> kbuf
  zgen<<<16384, 256, 0, stream>>>(x, mx_k, zbuf);
  gemm_bt<ACT_TANH><<<256, 512, 0, stream>>>(zbuf, Wb + 2 * 1048576, kbuf, nullptr, nullptr);
  // kv = v * k -> vbuf
  zgen<<<16384, 256, 0, stream>>>(x, mx_v, zbuf);
  gemm_bt<ACT_VMUL><<<256, 512, 0, stream>>>(zbuf, Wb + 3 * 1048576, vbuf, kbuf, nullptr);
  // u = sigmoid(lin_a) * kv -> ubuf (bf16)
  zgen<<<16384, 256, 0, stream>>>(x, mx_a, zbuf);
  gemm_bt<ACT_U><<<256, 512, 0, stream>>>(zbuf, Wb + 4 * 1048576, ubuf, vbuf, nullptr);
  // r = sigmoid -> kbuf (reuse)
  zgen<<<16384, 256, 0, stream>>>(x, mx_r, zbuf);
  gemm_bt<ACT_SIG><<<256, 512, 0, stream>>>(zbuf, Wb + 0, kbuf, nullptr, nullptr);
  // g = sigmoid -> vbuf (reuse)
  zgen<<<16384, 256, 0, stream>>>(x, mx_g, zbuf);
  gemm_bt<ACT_SIG><<<256, 512, 0, stream>>>(zbuf, Wb + 5 * 1048576, vbuf, nullptr, nullptr);

  // recurrence (chunked parallel scan); mixed overwrites dec in scan3
  scan1<<<1024, 256, 0, stream>>>(dec, ubuf, Ac, Sc);
  scan2<<<16, 256, 0, stream>>>(Ac, Sc, Inb);
  scan3<<<1024, 256, 0, stream>>>(dec, ubuf, kbuf, Inb);

  // groupnorm(mixed) * g -> h (bf16, into zbuf)
  gnorm<<<65536, 256, 0, stream>>>(dec, vbuf, gn_w, gn_b, zbuf);

  // out = h @ W_out^T + b_out, f32
  gemm_bt<ACT_BIAS><<<256, 512, 0, stream>>>(zbuf, Wb + 6 * 1048576, (float*)d_out, nullptr, b_out);
}

// Round 7
// 514.207 us; speedup vs baseline: 1.3447x; 1.1017x over previous
//
#include <hip/hip_runtime.h>
#include <cstdint>
#include <cstddef>

#define D_MODEL 1024
#define SEQ_LEN 4096
#define NBATCH  4
#define M_ROWS  (NBATCH * SEQ_LEN)   // 16384 rows (b*4096+n)
#define NCHUNK  64
#define CHLEN   64                   // SEQ_LEN / NCHUNK
#define GN_EPS_F 0.00064f

typedef unsigned short u16;
typedef __attribute__((ext_vector_type(4))) float f32x4;
typedef __attribute__((ext_vector_type(8))) __bf16 bf16x8;

enum { ACT_DECAY = 0, ACT_TANH, ACT_VMUL, ACT_U, ACT_SIG, ACT_BIAS, ACT_ID };

__device__ __forceinline__ u16 f2bf(float f) {
  union { float f; uint32_t u; } un; un.f = f;
  uint32_t r = (un.u + 0x7FFFu + ((un.u >> 16) & 1u)) >> 16;  // RNE
  return (u16)r;
}
__device__ __forceinline__ float bf2f(u16 h) {
  union { uint32_t u; float f; } un; un.u = ((uint32_t)h) << 16;
  return un.f;
}
__device__ __forceinline__ float sigm(float y) { return 1.f / (1.f + expf(-y)); }

// async global->LDS, 16B/lane. LDS dst = wave-uniform base (HW adds lane*16).
__device__ __forceinline__ void load_lds16(const u16* g, u16* l) {
  __builtin_amdgcn_global_load_lds(
      (const __attribute__((address_space(1))) void*)g,
      (__attribute__((address_space(3))) void*)l, 16, 0, 0);
}

// ---------------- weights f32 -> bf16 (7 matrices, contiguous slots) ----------
__global__ __launch_bounds__(256) void wconv(
    const float* __restrict__ w0, const float* __restrict__ w1,
    const float* __restrict__ w2, const float* __restrict__ w3,
    const float* __restrict__ w4, const float* __restrict__ w5,
    const float* __restrict__ w6, u16* __restrict__ Wb) {
  const int gid = blockIdx.x * 256 + threadIdx.x;  // over 7*262144 float4s
  const int m = gid >> 18;
  const int off = gid & 262143;
  const float* src;
  switch (m) {
    case 0: src = w0; break; case 1: src = w1; break; case 2: src = w2; break;
    case 3: src = w3; break; case 4: src = w4; break; case 5: src = w5; break;
    default: src = w6; break;
  }
  const float4 v = ((const float4*)src)[off];
  ushort4 o;
  o.x = f2bf(v.x); o.y = f2bf(v.y); o.z = f2bf(v.z); o.w = f2bf(v.w);
  ((ushort4*)Wb)[gid] = o;
}

// -------- z = x + (prev - x) * mix for TWO mixes in one x pass -> bf16 -------
__global__ __launch_bounds__(256) void zgen2(
    const float* __restrict__ x, const float* __restrict__ mixA,
    const float* __restrict__ mixB, u16* __restrict__ zA,
    u16* __restrict__ zB) {
  const int gid = blockIdx.x * 256 + threadIdx.x;  // over M_ROWS*D/4 = 4,194,304
  const int dv = gid & 255;                        // float4 index within row
  const int n = (gid >> 8) & (SEQ_LEN - 1);
  const float4 xv = ((const float4*)x)[gid];
  float4 pv = make_float4(0.f, 0.f, 0.f, 0.f);
  if (n > 0) pv = ((const float4*)x)[gid - 256];   // previous token, same batch
  const float4 dxv = make_float4(pv.x - xv.x, pv.y - xv.y, pv.z - xv.z, pv.w - xv.w);
  const float4 ma = ((const float4*)mixA)[dv];
  const float4 mb = ((const float4*)mixB)[dv];
  ushort4 oa, ob;
  oa.x = f2bf(xv.x + dxv.x * ma.x); ob.x = f2bf(xv.x + dxv.x * mb.x);
  oa.y = f2bf(xv.y + dxv.y * ma.y); ob.y = f2bf(xv.y + dxv.y * mb.y);
  oa.z = f2bf(xv.z + dxv.z * ma.z); ob.z = f2bf(xv.z + dxv.z * mb.z);
  oa.w = f2bf(xv.w + dxv.w * ma.w); ob.w = f2bf(xv.w + dxv.w * mb.w);
  ((ushort4*)zA)[gid] = oa;
  ((ushort4*)zB)[gid] = ob;
}

// ---------------- bf16 GEMM: out = A @ W^T, 256x256 8-phase schedule ---------
// 256x256 tile, BK=64, 8 waves (2Mx4N), 512 thr, LDS 128KB (2 dbuf).
// Counted vmcnt only; raw s_barrier; sched pin only at P1 (freshness barrier).
// LDS swizzle: linear dest + inverse-swizzled global source + swizzled read.
template <int ACT>
__global__ __launch_bounds__(512, 2) void gemm_bt(
    const u16* __restrict__ A,   // [M][1024] bf16
    const u16* __restrict__ Bw,  // [1024][1024] bf16 row-major (torch W)
    void* __restrict__ outp,
    const u16* __restrict__ aux,     // kv for ACT_U, k for ACT_VMUL
    const float* __restrict__ bias) {  // for ACT_BIAS
  __shared__ __align__(16) u16 AL[2][256 * 64];   // 64 KB
  __shared__ __align__(16) u16 BL[2][256 * 64];   // 64 KB
  const int tid = threadIdx.x;
  const int lane = tid & 63;
  const int wid = tid >> 6;          // 0..7
  const int wr = wid >> 2;           // 0..1  (M half)
  const int wc = wid & 3;            // 0..3  (N quarter)
  const int lr = lane & 15;
  const int lk = lane >> 4;

  // XCD-chunked swizzle: 256 blocks, 8 XCDs, 32 contiguous logical tiles each
  const int bid = blockIdx.x;
  const int logical = (bid & 7) * 32 + (bid >> 3);
  const int m0 = (logical >> 2) * 256;
  const int n0 = (logical & 3) * 256;

  // staging: thread t: row = t>>3, 16B-chunk = (t&7) ^ (row&7) (pre-swizzled)
  const int srow = tid >> 3;
  const int ssw  = ((tid & 7) ^ (srow & 7)) * 8;   // u16 col offset
  const u16* gA = A  + (size_t)(m0 + srow) * D_MODEL + ssw;
  const u16* gB = Bw + (size_t)(n0 + srow) * D_MODEL + ssw;
#define SA(g, bufi, kt) load_lds16(gA + (size_t)(g)*64*D_MODEL + (kt), &AL[bufi][(g)*4096 + wid*512])
#define SB(g, bufi, kt) load_lds16(gB + (size_t)(g)*64*D_MODEL + (kt), &BL[bufi][(g)*4096 + wid*512])

  // ds_read: row R -> u16 R*64 + swizzled chunk ((kk*4+lk)^(R&7))*8
  const int rbA = (wr * 128 + lr) * 64;
  const int rbB = (wc * 64 + lr) * 64;
  const int sw0 = ((lk)     ^ (lr & 7)) << 3;
  const int sw1 = ((lk + 4) ^ (lr & 7)) << 3;

  f32x4 acc[8][4];
  const f32x4 z4 = {0.f, 0.f, 0.f, 0.f};
#pragma unroll
  for (int i = 0; i < 8; i++)
#pragma unroll
    for (int j = 0; j < 4; j++) acc[i][j] = z4;

  // prologue: tile 0 into buf 0, issue order = consumption order
  SB(0, 0, 0); SB(1, 0, 0); SB(2, 0, 0); SB(3, 0, 0);
  SA(0, 0, 0); SA(2, 0, 0); SA(1, 0, 0); SA(3, 0, 0);

  int cur = 0;
  for (int t = 0; t < 16; ++t) {
    const int nxt = cur ^ 1;
    const int ktn = (t + 1) * 64;
    const bool more = (t < 15);
    const u16* uA = AL[cur];
    const u16* uB = BL[cur];
    bf16x8 a0[4][2], a1[4][2], b[4][2];

    // ---- P1: quadrant (mh=0, nj=0..1)
    if (more) { SB(0, nxt, ktn); SB(1, nxt, ktn); }
    if (more) asm volatile("s_waitcnt vmcnt(4)" ::: "memory");  // t: B0-3,A0,A2 landed
    else      asm volatile("s_waitcnt vmcnt(2)" ::: "memory");
    __builtin_amdgcn_s_barrier();
    __builtin_amdgcn_sched_barrier(0);   // freshness-critical: no read hoists above
#pragma unroll
    for (int mi = 0; mi < 4; ++mi) {
      a0[mi][0] = *(const bf16x8*)&uA[rbA + mi * 1024 + sw0];
      a0[mi][1] = *(const bf16x8*)&uA[rbA + mi * 1024 + sw1];
    }
#pragma unroll
    for (int nj = 0; nj < 2; ++nj) {
      b[nj][0] = *(const bf16x8*)&uB[rbB + nj * 1024 + sw0];
      b[nj][1] = *(const bf16x8*)&uB[rbB + nj * 1024 + sw1];
    }
    __builtin_amdgcn_s_setprio(1);
#pragma unroll
    for (int mi = 0; mi < 4; ++mi)
#pragma unroll
      for (int nj = 0; nj < 2; ++nj)
#pragma unroll
        for (int kk = 0; kk < 2; ++kk)
          acc[mi][nj] = __builtin_amdgcn_mfma_f32_16x16x32_bf16(a0[mi][kk], b[nj][kk], acc[mi][nj], 0, 0, 0);
    __builtin_amdgcn_s_setprio(0);

    // ---- P2: quadrant (mh=0, nj=2..3)  (data valid since P1 barrier)
#pragma unroll
    for (int nj = 2; nj < 4; ++nj) {
      b[nj][0] = *(const bf16x8*)&uB[rbB + nj * 1024 + sw0];
      b[nj][1] = *(const bf16x8*)&uB[rbB + nj * 1024 + sw1];
    }
    if (more) { SB(2, nxt, ktn); SB(3, nxt, ktn); }
    __builtin_amdgcn_s_barrier();
    __builtin_amdgcn_s_setprio(1);
#pragma unroll
    for (int mi = 0; mi < 4; ++mi)
#pragma unroll
      for (int nj = 2; nj < 4; ++nj)
#pragma unroll
        for (int kk = 0; kk < 2; ++kk)
          acc[mi][nj] = __builtin_amdgcn_mfma_f32_16x16x32_bf16(a0[mi][kk], b[nj][kk], acc[mi][nj], 0, 0, 0);
    __builtin_amdgcn_s_setprio(0);

    // ---- P3: quadrant (mh=1, nj=0..1)
#pragma unroll
    for (int mi = 0; mi < 4; ++mi) {
      a1[mi][0] = *(const bf16x8*)&uA[rbA + 4096 + mi * 1024 + sw0];
      a1[mi][1] = *(const bf16x8*)&uA[rbA + 4096 + mi * 1024 + sw1];
    }
    if (more) { SA(0, nxt, ktn); SA(2, nxt, ktn); }
    if (more) asm volatile("s_waitcnt vmcnt(6)" ::: "memory");  // t: A1,A3 landed
    else      asm volatile("s_waitcnt vmcnt(0)" ::: "memory");
    __builtin_amdgcn_s_barrier();
    __builtin_amdgcn_s_setprio(1);
#pragma unroll
    for (int mi = 0; mi < 4; ++mi)
#pragma unroll
      for (int nj = 0; nj < 2; ++nj)
#pragma unroll
        for (int kk = 0; kk < 2; ++kk)
          acc[4 + mi][nj] = __builtin_amdgcn_mfma_f32_16x16x32_bf16(a1[mi][kk], b[nj][kk], acc[4 + mi][nj], 0, 0, 0);
    __builtin_amdgcn_s_setprio(0);

    // ---- P4: quadrant (mh=1, nj=2..3)
    if (more) { SA(1, nxt, ktn); SA(3, nxt, ktn); }
    __builtin_amdgcn_s_barrier();
    __builtin_amdgcn_s_setprio(1);
#pragma unroll
    for (int mi = 0; mi < 4; ++mi)
#pragma unroll
      for (int nj = 2; nj < 4; ++nj)
#pragma unroll
        for (int kk = 0; kk < 2; ++kk)
          acc[4 + mi][nj] = __builtin_amdgcn_mfma_f32_16x16x32_bf16(a1[mi][kk], b[nj][kk], acc[4 + mi][nj], 0, 0, 0);
    __builtin_amdgcn_s_setprio(0);
    cur = nxt;
  }
#undef SA
#undef SB

  // epilogue; C/D layout: col = lane&15, row = (lane>>4)*4 + e  [m89-verified]
#pragma unroll
  for (int mh = 0; mh < 2; ++mh) {
#pragma unroll
    for (int mi = 0; mi < 4; ++mi) {
#pragma unroll
      for (int nj = 0; nj < 4; ++nj) {
#pragma unroll
        for (int e = 0; e < 4; ++e) {
          const int row = m0 + wr * 128 + mh * 64 + mi * 16 + lk * 4 + e;
          const int col = n0 + wc * 64 + nj * 16 + lr;
          const size_t idx = (size_t)row * D_MODEL + col;
          const float y = acc[mh * 4 + mi][nj][e];
          if constexpr (ACT == ACT_ID) {
            ((u16*)outp)[idx] = f2bf(y);                           // raw lin (w)
          } else if constexpr (ACT == ACT_TANH) {
            ((u16*)outp)[idx] = f2bf(tanhf(y));
          } else if constexpr (ACT == ACT_VMUL) {
            ((u16*)outp)[idx] = f2bf(y * bf2f(aux[idx]));          // kv = v * k
          } else if constexpr (ACT == ACT_U) {
            ((u16*)outp)[idx] = f2bf(sigm(y) * bf2f(aux[idx]));    // u = alpha * kv
          } else if constexpr (ACT == ACT_SIG) {
            ((u16*)outp)[idx] = f2bf(sigm(y));
          } else {  // ACT_BIAS
            ((float*)outp)[idx] = y + bias[col];
          }
        }
      }
    }
  }
}

// ---------------- chunked scan: state = state*decay + u; mixed = r*state -----
// decay = sigmoid(-y) computed on the fly from raw bf16 y (VALU is idle here).
__global__ __launch_bounds__(256) void scan1(
    const u16* __restrict__ wraw, const u16* __restrict__ u,
    float* __restrict__ Ac, float* __restrict__ Sc) {
  const int gid = blockIdx.x * 256 + threadIdx.x;  // c*4096 + b*1024 + d
  const int d = gid & 1023;
  const int b = (gid >> 10) & 3;
  const int c = gid >> 12;
  const size_t base = ((size_t)b * SEQ_LEN + (size_t)c * CHLEN) * D_MODEL + d;
  float A = 1.f, S = 0.f;
#pragma unroll 4
  for (int t = 0; t < CHLEN; t++) {
    const size_t off = base + (size_t)t * D_MODEL;
    const float dd = 1.f / (1.f + expf(bf2f(wraw[off])));  // sigmoid(-y)
    S = S * dd + bf2f(u[off]);
    A *= dd;
  }
  Ac[gid] = A;
  Sc[gid] = S;
}

__global__ __launch_bounds__(256) void scan2(
    const float* __restrict__ Ac, const float* __restrict__ Sc,
    float* __restrict__ In) {
  const int gid = blockIdx.x * 256 + threadIdx.x;  // b*1024 + d, 4096 total
  float carry = 0.f;
#pragma unroll 4
  for (int c = 0; c < NCHUNK; c++) {
    const int i = c * 4096 + gid;
    In[i] = carry;
    carry = carry * Ac[i] + Sc[i];
  }
}

__global__ __launch_bounds__(256) void scan3(
    const u16* __restrict__ wraw, const u16* __restrict__ u,
    const u16* __restrict__ r, const float* __restrict__ In,
    u16* __restrict__ mixed) {
  const int gid = blockIdx.x * 256 + threadIdx.x;
  const int d = gid & 1023;
  const int b = (gid >> 10) & 3;
  const int c = gid >> 12;
  const size_t base = ((size_t)b * SEQ_LEN + (size_t)c * CHLEN) * D_MODEL + d;
  float state = In[gid];
#pragma unroll 4
  for (int t = 0; t < CHLEN; t++) {
    const size_t off = base + (size_t)t * D_MODEL;
    const float dd = 1.f / (1.f + expf(bf2f(wraw[off])));  // sigmoid(-y)
    state = state * dd + bf2f(u[off]);
    mixed[off] = f2bf(bf2f(r[off]) * state);
  }
}

// ---------------- GroupNorm(H=16, 64ch) * g -> bf16 ---------------------------
__global__ __launch_bounds__(256) void gnorm(
    const u16* __restrict__ mixed, const u16* __restrict__ g,
    const float* __restrict__ gw, const float* __restrict__ gb,
    u16* __restrict__ h) {
  const int wid = threadIdx.x >> 6;
  const int lane = threadIdx.x & 63;
  const int grp = blockIdx.x * 4 + wid;  // over M_ROWS*16 = 262144
  const int row = grp >> 4;
  const int hh = grp & 15;
  const int d = hh * 64 + lane;
  const size_t idx = (size_t)row * D_MODEL + d;
  const float v = bf2f(mixed[idx]);
  float s = v, s2 = v * v;
#pragma unroll
  for (int m = 32; m > 0; m >>= 1) {
    s += __shfl_xor(s, m, 64);
    s2 += __shfl_xor(s2, m, 64);
  }
  const float mu = s * (1.f / 64.f);
  float var = s2 * (1.f / 64.f) - mu * mu;
  const float inv = 1.f / sqrtf(var + GN_EPS_F);
  const float mn = (v - mu) * inv * gw[d] + gb[d];
  h[idx] = f2bf(mn * bf2f(g[idx]));
}

// ---------------- host ---------------------------------------------------------
extern "C" void kernel_launch(void* const* d_in, const int* in_sizes, int n_in,
                              void* d_out, int out_size, void* d_ws, size_t ws_size,
                              hipStream_t stream) {
  (void)in_sizes; (void)n_in; (void)out_size; (void)ws_size;
  const float* x    = (const float*)d_in[0];
  const float* mx_r = (const float*)d_in[1];
  const float* mx_w = (const float*)d_in[2];
  const float* mx_k = (const float*)d_in[3];
  const float* mx_v = (const float*)d_in[4];
  const float* mx_a = (const float*)d_in[5];
  const float* mx_g = (const float*)d_in[6];
  const float* W_r  = (const float*)d_in[7];
  const float* W_w  = (const float*)d_in[8];
  const float* W_k  = (const float*)d_in[9];
  const float* W_v  = (const float*)d_in[10];
  const float* W_a  = (const float*)d_in[11];
  const float* W_g  = (const float*)d_in[12];
  const float* W_o  = (const float*)d_in[13];
  const float* b_out = (const float*)d_in[14];
  const float* gn_w  = (const float*)d_in[15];
  const float* gn_b  = (const float*)d_in[16];

  // Workspace plan (209 MB; all bf16 intermediates):
  //   0: Wb 14 | 14: Ac 1 | 15: Sc 1 | 16: z1 32 (z; later mixed bf16)
  //   48: z2 32 (z; later h) | 80: wraw 32 (lin_w bf16) | 112: ubuf 32
  //   144: kbuf 32 (k; later r) | 176: vbuf 32 (kv; later g) | 208: In 1
  char* ws = (char*)d_ws;
  const size_t MB = 1024ull * 1024ull;
  u16*   Wb   = (u16*)(ws);
  float* Ac   = (float*)(ws + 14 * MB);
  float* Sc   = (float*)(ws + 15 * MB);
  u16*   z1   = (u16*)(ws + 16 * MB);
  u16*   z2   = (u16*)(ws + 48 * MB);
  u16*   wraw = (u16*)(ws + 80 * MB);
  u16*   ubuf = (u16*)(ws + 112 * MB);
  u16*   kbuf = (u16*)(ws + 144 * MB);
  u16*   vbuf = (u16*)(ws + 176 * MB);
  float* Inb  = (float*)(ws + 208 * MB);

  wconv<<<7168, 256, 0, stream>>>(W_r, W_w, W_k, W_v, W_a, W_g, W_o, Wb);

  // pair 1: z_w, z_k
  zgen2<<<16384, 256, 0, stream>>>(x, mx_w, mx_k, z1, z2);
  gemm_bt<ACT_ID><<<256, 512, 0, stream>>>(z1, Wb + 1 * 1048576, wraw, nullptr, nullptr);
  gemm_bt<ACT_TANH><<<256, 512, 0, stream>>>(z2, Wb + 2 * 1048576, kbuf, nullptr, nullptr);
  // pair 2: z_v, z_a
  zgen2<<<16384, 256, 0, stream>>>(x, mx_v, mx_a, z1, z2);
  gemm_bt<ACT_VMUL><<<256, 512, 0, stream>>>(z1, Wb + 3 * 1048576, vbuf, kbuf, nullptr);
  gemm_bt<ACT_U><<<256, 512, 0, stream>>>(z2, Wb + 4 * 1048576, ubuf, vbuf, nullptr);
  // pair 3: z_r, z_g
  zgen2<<<16384, 256, 0, stream>>>(x, mx_r, mx_g, z1, z2);
  gemm_bt<ACT_SIG><<<256, 512, 0, stream>>>(z1, Wb + 0, kbuf, nullptr, nullptr);
  gemm_bt<ACT_SIG><<<256, 512, 0, stream>>>(z2, Wb + 5 * 1048576, vbuf, nullptr, nullptr);

  // recurrence (chunked parallel scan); mixed (bf16) -> z1
  scan1<<<1024, 256, 0, stream>>>(wraw, ubuf, Ac, Sc);
  scan2<<<16, 256, 0, stream>>>(Ac, Sc, Inb);
  scan3<<<1024, 256, 0, stream>>>(wraw, ubuf, kbuf, Inb, z1);

  // groupnorm(mixed) * g -> h (bf16, into z2)
  gnorm<<<65536, 256, 0, stream>>>(z1, vbuf, gn_w, gn_b, z2);

  // out = h @ W_out^T + b_out, f32
  gemm_bt<ACT_BIAS><<<256, 512, 0, stream>>>(z2, Wb + 6 * 1048576, (float*)d_out, nullptr, b_out);
}

// Round 8
// 497.416 us; speedup vs baseline: 1.3901x; 1.0338x over previous
//
#include <hip/hip_runtime.h>
#include <cstdint>
#include <cstddef>

#define D_MODEL 1024
#define SEQ_LEN 4096
#define NBATCH  4
#define M_ROWS  (NBATCH * SEQ_LEN)   // 16384 rows (b*4096+n)
#define NCHUNK  64
#define CHLEN   64                   // SEQ_LEN / NCHUNK
#define GN_EPS_F 0.00064f

typedef unsigned short u16;
typedef __attribute__((ext_vector_type(4))) float f32x4;
typedef __attribute__((ext_vector_type(8))) __bf16 bf16x8;

enum { ACT_DECAY = 0, ACT_TANH, ACT_VMUL, ACT_U, ACT_SIG, ACT_BIAS, ACT_ID };

__device__ __forceinline__ u16 f2bf(float f) {
  union { float f; uint32_t u; } un; un.f = f;
  uint32_t r = (un.u + 0x7FFFu + ((un.u >> 16) & 1u)) >> 16;  // RNE
  return (u16)r;
}
__device__ __forceinline__ float bf2f(u16 h) {
  union { uint32_t u; float f; } un; un.u = ((uint32_t)h) << 16;
  return un.f;
}
__device__ __forceinline__ float sigm(float y) { return 1.f / (1.f + expf(-y)); }

// async global->LDS, 16B/lane. LDS dst = wave-uniform base (HW adds lane*16).
__device__ __forceinline__ void load_lds16(const u16* g, u16* l) {
  __builtin_amdgcn_global_load_lds(
      (const __attribute__((address_space(1))) void*)g,
      (__attribute__((address_space(3))) void*)l, 16, 0, 0);
}

// ---------------- weights f32 -> bf16 (7 matrices, contiguous slots) ----------
__global__ __launch_bounds__(256) void wconv(
    const float* __restrict__ w0, const float* __restrict__ w1,
    const float* __restrict__ w2, const float* __restrict__ w3,
    const float* __restrict__ w4, const float* __restrict__ w5,
    const float* __restrict__ w6, u16* __restrict__ Wb) {
  const int gid = blockIdx.x * 256 + threadIdx.x;  // over 7*262144 float4s
  const int m = gid >> 18;
  const int off = gid & 262143;
  const float* src;
  switch (m) {
    case 0: src = w0; break; case 1: src = w1; break; case 2: src = w2; break;
    case 3: src = w3; break; case 4: src = w4; break; case 5: src = w5; break;
    default: src = w6; break;
  }
  const float4 v = ((const float4*)src)[off];
  ushort4 o;
  o.x = f2bf(v.x); o.y = f2bf(v.y); o.z = f2bf(v.z); o.w = f2bf(v.w);
  ((ushort4*)Wb)[gid] = o;
}

// -------- z = x + (prev - x) * mix for TWO mixes in one x pass -> bf16 -------
__global__ __launch_bounds__(256) void zgen2(
    const float* __restrict__ x, const float* __restrict__ mixA,
    const float* __restrict__ mixB, u16* __restrict__ zA,
    u16* __restrict__ zB) {
  const int gid = blockIdx.x * 256 + threadIdx.x;  // over M_ROWS*D/4 = 4,194,304
  const int dv = gid & 255;                        // float4 index within row
  const int n = (gid >> 8) & (SEQ_LEN - 1);
  const float4 xv = ((const float4*)x)[gid];
  float4 pv = make_float4(0.f, 0.f, 0.f, 0.f);
  if (n > 0) pv = ((const float4*)x)[gid - 256];   // previous token, same batch
  const float4 dxv = make_float4(pv.x - xv.x, pv.y - xv.y, pv.z - xv.z, pv.w - xv.w);
  const float4 ma = ((const float4*)mixA)[dv];
  const float4 mb = ((const float4*)mixB)[dv];
  ushort4 oa, ob;
  oa.x = f2bf(xv.x + dxv.x * ma.x); ob.x = f2bf(xv.x + dxv.x * mb.x);
  oa.y = f2bf(xv.y + dxv.y * ma.y); ob.y = f2bf(xv.y + dxv.y * mb.y);
  oa.z = f2bf(xv.z + dxv.z * ma.z); ob.z = f2bf(xv.z + dxv.z * mb.z);
  oa.w = f2bf(xv.w + dxv.w * ma.w); ob.w = f2bf(xv.w + dxv.w * mb.w);
  ((ushort4*)zA)[gid] = oa;
  ((ushort4*)zB)[gid] = ob;
}

// ---------------- bf16 GEMM: out = A @ W^T ----------------------------------
// 128x256 tile, BK=32, 8 waves (2Mx4N, 64x64/wave), 512 thr, LDS 48KB ->
// 2 blocks/CU co-residency (the stall-overlap mechanism). 2 phases/K-tile,
// counted vmcnt(2) (1 A-load + 2 B-loads per tile in flight), raw s_barrier,
// setprio on MFMA. Swizzle: chunk ^= (row>>1)&3 within 64B rows -> 2-way
// bank aliasing (free). Pre-swizzled global source + swizzled ds_read.
template <int ACT>
__global__ __launch_bounds__(512, 4) void gemm_bt(
    const u16* __restrict__ A,   // [M][1024] bf16
    const u16* __restrict__ Bw,  // [1024][1024] bf16 row-major (torch W)
    void* __restrict__ outp,
    const u16* __restrict__ aux,     // kv for ACT_U, k for ACT_VMUL
    const float* __restrict__ bias) {  // for ACT_BIAS
  __shared__ __align__(16) u16 AL[2][128 * 32];   // 8 KB each
  __shared__ __align__(16) u16 BL[2][256 * 32];   // 16 KB each
  const int tid = threadIdx.x;
  const int lane = tid & 63;
  const int wid = tid >> 6;          // 0..7
  const int wr = wid >> 2;           // 0..1  (M half, 64 rows)
  const int wc = wid & 3;            // 0..3  (N quarter, 64 cols)
  const int lr = lane & 15;
  const int lk = lane >> 4;

  // XCD-chunked swizzle: 512 blocks, 8 XCDs, 64 contiguous logical tiles each
  const int bid = blockIdx.x;
  const int wgid = (bid & 7) * 64 + (bid >> 3);
  const int m0 = (wgid >> 2) * 128;
  const int n0 = (wgid & 3) * 256;

  // staging: thread t -> row t>>2 (0..127), 16B-chunk (t&3) ^ ((row>>1)&3)
  const int srow = tid >> 2;
  const int ssw  = ((tid & 3) ^ ((srow >> 1) & 3)) * 8;   // u16 col offset
  const u16* gA  = A  + (size_t)(m0 + srow) * D_MODEL + ssw;
  const u16* gB0 = Bw + (size_t)(n0 + srow) * D_MODEL + ssw;
  const u16* gB1 = Bw + (size_t)(n0 + 128 + srow) * D_MODEL + ssw;
#define SA(bufi, kt) load_lds16(gA  + (kt), &AL[bufi][wid * 512])
#define SB0(bufi, kt) load_lds16(gB0 + (kt), &BL[bufi][wid * 512])
#define SB1(bufi, kt) load_lds16(gB1 + (kt), &BL[bufi][4096 + wid * 512])

  // ds_read: local row R -> u16 R*32 + ((lk ^ ((R>>1)&3))<<3)
  const int rA = wr * 64;
  const int rB = wc * 64;

  f32x4 acc[4][4];
  const f32x4 z4 = {0.f, 0.f, 0.f, 0.f};
#pragma unroll
  for (int i = 0; i < 4; i++)
#pragma unroll
    for (int j = 0; j < 4; j++) acc[i][j] = z4;

  // prologue: tile 0 into buf 0
  SB0(0, 0); SB1(0, 0); SA(0, 0);

  int cur = 0;
  for (int t = 0; t < 32; ++t) {
    const int nxt = cur ^ 1;
    const int ktn = (t + 1) * 32;
    const bool more = (t < 31);
    const u16* uA = AL[cur];
    const u16* uB = BL[cur];
    bf16x8 a[4], b[4];

    // ---- P1: issue next B; wait tile t's 3; read all frags; MFMA nj 0..1
    if (more) { SB0(nxt, ktn); SB1(nxt, ktn); }
    if (more) asm volatile("s_waitcnt vmcnt(2)" ::: "memory");
    else      asm volatile("s_waitcnt vmcnt(0)" ::: "memory");
    __builtin_amdgcn_s_barrier();
    __builtin_amdgcn_sched_barrier(0);   // no ds_read hoists above the barrier
#pragma unroll
    for (int mi = 0; mi < 4; ++mi) {
      const int R = rA + mi * 16 + lr;
      a[mi] = *(const bf16x8*)&uA[R * 32 + ((lk ^ ((R >> 1) & 3)) << 3)];
    }
#pragma unroll
    for (int nj = 0; nj < 4; ++nj) {
      const int R = rB + nj * 16 + lr;
      b[nj] = *(const bf16x8*)&uB[R * 32 + ((lk ^ ((R >> 1) & 3)) << 3)];
    }
    __builtin_amdgcn_s_setprio(1);
#pragma unroll
    for (int mi = 0; mi < 4; ++mi)
#pragma unroll
      for (int nj = 0; nj < 2; ++nj)
        acc[mi][nj] = __builtin_amdgcn_mfma_f32_16x16x32_bf16(a[mi], b[nj], acc[mi][nj], 0, 0, 0);
    __builtin_amdgcn_s_setprio(0);

    // ---- P2: issue next A; MFMA nj 2..3
    if (more) SA(nxt, ktn);
    __builtin_amdgcn_s_barrier();
    __builtin_amdgcn_s_setprio(1);
#pragma unroll
    for (int mi = 0; mi < 4; ++mi)
#pragma unroll
      for (int nj = 2; nj < 4; ++nj)
        acc[mi][nj] = __builtin_amdgcn_mfma_f32_16x16x32_bf16(a[mi], b[nj], acc[mi][nj], 0, 0, 0);
    __builtin_amdgcn_s_setprio(0);
    cur = nxt;
  }
#undef SA
#undef SB0
#undef SB1

  // epilogue; C/D layout: col = lane&15, row = (lane>>4)*4 + e  [m89-verified]
#pragma unroll
  for (int mi = 0; mi < 4; ++mi) {
#pragma unroll
    for (int nj = 0; nj < 4; ++nj) {
#pragma unroll
      for (int e = 0; e < 4; ++e) {
        const int row = m0 + wr * 64 + mi * 16 + lk * 4 + e;
        const int col = n0 + wc * 64 + nj * 16 + lr;
        const size_t idx = (size_t)row * D_MODEL + col;
        const float y = acc[mi][nj][e];
        if constexpr (ACT == ACT_ID) {
          ((u16*)outp)[idx] = f2bf(y);                           // raw lin (w)
        } else if constexpr (ACT == ACT_TANH) {
          ((u16*)outp)[idx] = f2bf(tanhf(y));
        } else if constexpr (ACT == ACT_VMUL) {
          ((u16*)outp)[idx] = f2bf(y * bf2f(aux[idx]));          // kv = v * k
        } else if constexpr (ACT == ACT_U) {
          ((u16*)outp)[idx] = f2bf(sigm(y) * bf2f(aux[idx]));    // u = alpha * kv
        } else if constexpr (ACT == ACT_SIG) {
          ((u16*)outp)[idx] = f2bf(sigm(y));
        } else {  // ACT_BIAS
          ((float*)outp)[idx] = y + bias[col];
        }
      }
    }
  }
}

// ---------------- chunked scan passes 1-2 ------------------------------------
__global__ __launch_bounds__(256) void scan1(
    const u16* __restrict__ wraw, const u16* __restrict__ u,
    float* __restrict__ Ac, float* __restrict__ Sc) {
  const int gid = blockIdx.x * 256 + threadIdx.x;  // c*4096 + b*1024 + d
  const int d = gid & 1023;
  const int b = (gid >> 10) & 3;
  const int c = gid >> 12;
  const size_t base = ((size_t)b * SEQ_LEN + (size_t)c * CHLEN) * D_MODEL + d;
  float A = 1.f, S = 0.f;
#pragma unroll 4
  for (int t = 0; t < CHLEN; t++) {
    const size_t off = base + (size_t)t * D_MODEL;
    const float dd = 1.f / (1.f + expf(bf2f(wraw[off])));  // sigmoid(-y)
    S = S * dd + bf2f(u[off]);
    A *= dd;
  }
  Ac[gid] = A;
  Sc[gid] = S;
}

__global__ __launch_bounds__(256) void scan2(
    const float* __restrict__ Ac, const float* __restrict__ Sc,
    float* __restrict__ In) {
  const int gid = blockIdx.x * 256 + threadIdx.x;  // b*1024 + d, 4096 total
  float carry = 0.f;
#pragma unroll 4
  for (int c = 0; c < NCHUNK; c++) {
    const int i = c * 4096 + gid;
    In[i] = carry;
    carry = carry * Ac[i] + Sc[i];
  }
}

// ------- fused scan3 + GroupNorm + g-mult: h = gn(r*state)*g -> bf16 ---------
// block = (b, chunk), 1024 threads = 16 waves; wave w == group w (64 channels),
// lane == channel. Per t: state update, then wave-shuffle stats, write h.
__global__ __launch_bounds__(1024) void scan3gn(
    const u16* __restrict__ wraw, const u16* __restrict__ u,
    const u16* __restrict__ r, const u16* __restrict__ g,
    const float* __restrict__ In, const float* __restrict__ gw,
    const float* __restrict__ gb, u16* __restrict__ h) {
  const int d = threadIdx.x;               // 0..1023
  const int b = blockIdx.x >> 6;           // 0..3
  const int c = blockIdx.x & 63;           // 0..63
  const size_t base = ((size_t)b * SEQ_LEN + (size_t)c * CHLEN) * D_MODEL + d;
  float state = In[c * 4096 + b * 1024 + d];
  const float w_ = gw[d], bb_ = gb[d];
  for (int t = 0; t < CHLEN; t++) {
    const size_t off = base + (size_t)t * D_MODEL;
    const float dd = 1.f / (1.f + expf(bf2f(wraw[off])));  // sigmoid(-y)
    state = state * dd + bf2f(u[off]);
    const float mixed = bf2f(r[off]) * state;
    float s = mixed, s2 = mixed * mixed;
#pragma unroll
    for (int m = 32; m > 0; m >>= 1) {
      s += __shfl_xor(s, m, 64);
      s2 += __shfl_xor(s2, m, 64);
    }
    const float mu = s * (1.f / 64.f);
    const float var = s2 * (1.f / 64.f) - mu * mu;
    const float inv = 1.f / sqrtf(var + GN_EPS_F);
    h[off] = f2bf(((mixed - mu) * inv * w_ + bb_) * bf2f(g[off]));
  }
}

// ---------------- host ---------------------------------------------------------
extern "C" void kernel_launch(void* const* d_in, const int* in_sizes, int n_in,
                              void* d_out, int out_size, void* d_ws, size_t ws_size,
                              hipStream_t stream) {
  (void)in_sizes; (void)n_in; (void)out_size; (void)ws_size;
  const float* x    = (const float*)d_in[0];
  const float* mx_r = (const float*)d_in[1];
  const float* mx_w = (const float*)d_in[2];
  const float* mx_k = (const float*)d_in[3];
  const float* mx_v = (const float*)d_in[4];
  const float* mx_a = (const float*)d_in[5];
  const float* mx_g = (const float*)d_in[6];
  const float* W_r  = (const float*)d_in[7];
  const float* W_w  = (const float*)d_in[8];
  const float* W_k  = (const float*)d_in[9];
  const float* W_v  = (const float*)d_in[10];
  const float* W_a  = (const float*)d_in[11];
  const float* W_g  = (const float*)d_in[12];
  const float* W_o  = (const float*)d_in[13];
  const float* b_out = (const float*)d_in[14];
  const float* gn_w  = (const float*)d_in[15];
  const float* gn_b  = (const float*)d_in[16];

  // Workspace plan (209 MB; all bf16 intermediates):
  //   0: Wb 14 | 14: Ac 1 | 15: Sc 1 | 16: z1 32 (z_w/z_v/z_r)
  //   48: z2 32 (z_k/z_a/z_g; later h) | 80: wraw 32 | 112: ubuf 32
  //   144: kbuf 32 (k; later r) | 176: vbuf 32 (kv; later g) | 208: In 1
  char* ws = (char*)d_ws;
  const size_t MB = 1024ull * 1024ull;
  u16*   Wb   = (u16*)(ws);
  float* Ac   = (float*)(ws + 14 * MB);
  float* Sc   = (float*)(ws + 15 * MB);
  u16*   z1   = (u16*)(ws + 16 * MB);
  u16*   z2   = (u16*)(ws + 48 * MB);
  u16*   wraw = (u16*)(ws + 80 * MB);
  u16*   ubuf = (u16*)(ws + 112 * MB);
  u16*   kbuf = (u16*)(ws + 144 * MB);
  u16*   vbuf = (u16*)(ws + 176 * MB);
  float* Inb  = (float*)(ws + 208 * MB);

  wconv<<<7168, 256, 0, stream>>>(W_r, W_w, W_k, W_v, W_a, W_g, W_o, Wb);

  // pair 1: z_w, z_k
  zgen2<<<16384, 256, 0, stream>>>(x, mx_w, mx_k, z1, z2);
  gemm_bt<ACT_ID><<<512, 512, 0, stream>>>(z1, Wb + 1 * 1048576, wraw, nullptr, nullptr);
  gemm_bt<ACT_TANH><<<512, 512, 0, stream>>>(z2, Wb + 2 * 1048576, kbuf, nullptr, nullptr);
  // pair 2: z_v, z_a
  zgen2<<<16384, 256, 0, stream>>>(x, mx_v, mx_a, z1, z2);
  gemm_bt<ACT_VMUL><<<512, 512, 0, stream>>>(z1, Wb + 3 * 1048576, vbuf, kbuf, nullptr);
  gemm_bt<ACT_U><<<512, 512, 0, stream>>>(z2, Wb + 4 * 1048576, ubuf, vbuf, nullptr);
  // pair 3: z_r, z_g
  zgen2<<<16384, 256, 0, stream>>>(x, mx_r, mx_g, z1, z2);
  gemm_bt<ACT_SIG><<<512, 512, 0, stream>>>(z1, Wb + 0, kbuf, nullptr, nullptr);
  gemm_bt<ACT_SIG><<<512, 512, 0, stream>>>(z2, Wb + 5 * 1048576, vbuf, nullptr, nullptr);

  // recurrence: chunk scan + fused finish (scan3+groupnorm+g), h -> z2
  scan1<<<1024, 256, 0, stream>>>(wraw, ubuf, Ac, Sc);
  scan2<<<16, 256, 0, stream>>>(Ac, Sc, Inb);
  scan3gn<<<256, 1024, 0, stream>>>(wraw, ubuf, kbuf, vbuf, Inb, gn_w, gn_b, z2);

  // out = h @ W_out^T + b_out, f32
  gemm_bt<ACT_BIAS><<<512, 512, 0, stream>>>(z2, Wb + 6 * 1048576, (float*)d_out, nullptr, b_out);
}